// Round 1
// baseline (1437.546 us; speedup 1.0000x reference)
//
#include <hip/hip_runtime.h>
#include <math.h>

#define NN 100000
#define NE 1600000
#define NF 128
#define NH 64

__global__ __launch_bounds__(256) void init_deg(float* deg, int n) {
    int i = blockIdx.x * 256 + threadIdx.x;
    if (i < n) deg[i] = 1.0f;
}

__global__ __launch_bounds__(256) void count_deg(const int* __restrict__ dst,
                                                 float* __restrict__ deg, int E) {
    int e = blockIdx.x * 256 + threadIdx.x;
    if (e < E) atomicAdd(&deg[dst[e]], 1.0f);
}

__global__ __launch_bounds__(256) void compute_dsq(const float* __restrict__ deg,
                                                   float* __restrict__ dsq, int n) {
    int i = blockIdx.x * 256 + threadIdx.x;
    if (i < n) dsq[i] = 1.0f / sqrtf(deg[i]);
}

// h = x @ W_emb + b_emb   (K=128, H=64). 256 thr = 4 waves, 4 rows/wave, 16 rows/block.
__global__ __launch_bounds__(256) void embed_gemm(const float* __restrict__ x,
                                                  const float* __restrict__ W,
                                                  const float* __restrict__ b,
                                                  float* __restrict__ h, int n) {
    __shared__ float Wl[NF * NH];
    for (int i = threadIdx.x; i < NF * NH; i += 256) Wl[i] = W[i];
    __syncthreads();
    int lane = threadIdx.x & 63;
    int wave = threadIdx.x >> 6;
    int row0 = blockIdx.x * 16 + wave * 4;
    float acc[4] = {0.f, 0.f, 0.f, 0.f};
    for (int k = 0; k < NF; ++k) {
        float wk = Wl[k * NH + lane];
#pragma unroll
        for (int r = 0; r < 4; ++r) {
            int row = min(row0 + r, n - 1);
            acc[r] += x[row * NF + k] * wk;
        }
    }
    float bl = b[lane];
#pragma unroll
    for (int r = 0; r < 4; ++r) {
        int row = row0 + r;
        if (row < n) h[row * NH + lane] = acc[r] + bl;
    }
}

// hw = h @ W ; agg = hw * dsq^2 + b   (K=64, H=64)
__global__ __launch_bounds__(256) void layer_gemm(const float* __restrict__ h,
                                                  const float* __restrict__ W,
                                                  const float* __restrict__ b,
                                                  const float* __restrict__ dsq,
                                                  float* __restrict__ hw,
                                                  float* __restrict__ agg, int n) {
    __shared__ float Wl[NH * NH];
    for (int i = threadIdx.x; i < NH * NH; i += 256) Wl[i] = W[i];
    __syncthreads();
    int lane = threadIdx.x & 63;
    int wave = threadIdx.x >> 6;
    int row0 = blockIdx.x * 16 + wave * 4;
    float acc[4] = {0.f, 0.f, 0.f, 0.f};
    for (int k = 0; k < NH; ++k) {
        float wk = Wl[k * NH + lane];
#pragma unroll
        for (int r = 0; r < 4; ++r) {
            int row = min(row0 + r, n - 1);
            acc[r] += h[row * NH + k] * wk;
        }
    }
    float bl = b[lane];
#pragma unroll
    for (int r = 0; r < 4; ++r) {
        int row = row0 + r;
        if (row < n) {
            hw[row * NH + lane] = acc[r];
            float ds = dsq[row];
            agg[row * NH + lane] = acc[r] * ds * ds + bl;
        }
    }
}

// one wave per edge; lane = feature. agg[dst] += hw[src] * dsq[src]*dsq[dst]
__global__ __launch_bounds__(256) void edge_scatter(const int* __restrict__ src,
                                                    const int* __restrict__ dst,
                                                    const float* __restrict__ dsq,
                                                    const float* __restrict__ hw,
                                                    float* __restrict__ agg, int E) {
    int tid = blockIdx.x * 256 + threadIdx.x;
    int e = tid >> 6;
    int f = tid & 63;
    if (e >= E) return;
    int s = src[e];
    int d = dst[e];
    float norm = dsq[s] * dsq[d];
    atomicAdd(&agg[d * NH + f], hw[s * NH + f] * norm);
}

__global__ __launch_bounds__(256) void relu_k(const float4* __restrict__ in,
                                              float4* __restrict__ out, int n4) {
    int i = blockIdx.x * 256 + threadIdx.x;
    if (i < n4) {
        float4 v = in[i];
        v.x = fmaxf(v.x, 0.f);
        v.y = fmaxf(v.y, 0.f);
        v.z = fmaxf(v.z, 0.f);
        v.w = fmaxf(v.w, 0.f);
        out[i] = v;
    }
}

extern "C" void kernel_launch(void* const* d_in, const int* in_sizes, int n_in,
                              void* d_out, int out_size, void* d_ws, size_t ws_size,
                              hipStream_t stream) {
    const float* x     = (const float*)d_in[0];
    const int*   ei    = (const int*)d_in[1];
    const float* W_emb = (const float*)d_in[2];
    const float* b_emb = (const float*)d_in[3];
    const float* Ws    = (const float*)d_in[4];
    const float* bs    = (const float*)d_in[5];
    float* out = (float*)d_out;

    const int* src = ei;
    const int* dst = ei + NE;

    float* ws  = (float*)d_ws;
    float* deg = ws;                  // NN
    float* dsq = ws + NN;             // NN
    float* A   = ws + 2 * NN;         // NN*NH  (h)
    float* B   = A + NN * NH;         // NN*NH  (hw)
    float* C   = B + NN * NH;         // NN*NH  (agg)

    init_deg<<<(NN + 255) / 256, 256, 0, stream>>>(deg, NN);
    count_deg<<<(NE + 255) / 256, 256, 0, stream>>>(dst, deg, NE);
    compute_dsq<<<(NN + 255) / 256, 256, 0, stream>>>(deg, dsq, NN);

    embed_gemm<<<(NN + 15) / 16, 256, 0, stream>>>(x, W_emb, b_emb, A, NN);

    for (int l = 0; l < 3; ++l) {
        layer_gemm<<<(NN + 15) / 16, 256, 0, stream>>>(
            A, Ws + l * NH * NH, bs + l * NH, dsq, B, C, NN);
        edge_scatter<<<(NE * 64) / 256, 256, 0, stream>>>(src, dst, dsq, B, C, NE);
        float* dbuf = (l == 2) ? out : A;
        relu_k<<<(NN * NH / 4 + 255) / 256, 256, 0, stream>>>(
            (const float4*)C, (float4*)dbuf, NN * NH / 4);
    }
}

// Round 2
// 945.193 us; speedup vs baseline: 1.5209x; 1.5209x over previous
//
#include <hip/hip_runtime.h>
#include <math.h>

#define NN 100000
#define NE 1600000
#define NF 128
#define NH 64
#define SCAN_T 1024

__global__ __launch_bounds__(256) void zero_cnt(int* cnt, int n) {
    int i = blockIdx.x * 256 + threadIdx.x;
    if (i < n) cnt[i] = 0;
}

__global__ __launch_bounds__(256) void count_deg(const int* __restrict__ dst,
                                                 int* __restrict__ cnt, int E) {
    int e = blockIdx.x * 256 + threadIdx.x;
    if (e < E) atomicAdd(&cnt[dst[e]], 1);
}

__global__ __launch_bounds__(256) void compute_dsq(const int* __restrict__ cnt,
                                                   float* __restrict__ dsq, int n) {
    int i = blockIdx.x * 256 + threadIdx.x;
    if (i < n) dsq[i] = rsqrtf((float)cnt[i] + 1.0f);  // +1 self-loop
}

// single-block exclusive scan of cnt -> rowptr (and cursor copy)
__global__ __launch_bounds__(SCAN_T) void scan_rowptr(const int* __restrict__ cnt,
                                                      int* __restrict__ rowptr,
                                                      int* __restrict__ cursor) {
    __shared__ int sums[SCAN_T];
    int t = threadIdx.x;
    const int chunk = (NN + SCAN_T - 1) / SCAN_T;  // 98
    int lo = t * chunk, hi = min(lo + chunk, NN);
    int s = 0;
    for (int i = lo; i < hi; ++i) s += cnt[i];
    sums[t] = s;
    __syncthreads();
    for (int off = 1; off < SCAN_T; off <<= 1) {
        int v = (t >= off) ? sums[t - off] : 0;
        __syncthreads();
        sums[t] += v;
        __syncthreads();
    }
    int run = (t == 0) ? 0 : sums[t - 1];
    for (int i = lo; i < hi; ++i) {
        rowptr[i] = run;
        cursor[i] = run;
        run += cnt[i];
    }
    if (t == SCAN_T - 1) rowptr[NN] = NE;
}

__global__ __launch_bounds__(256) void build_csr(const int* __restrict__ src,
                                                 const int* __restrict__ dst,
                                                 const float* __restrict__ dsq,
                                                 int* __restrict__ cursor,
                                                 int* __restrict__ csr_src,
                                                 float* __restrict__ csr_w, int E) {
    int e = blockIdx.x * 256 + threadIdx.x;
    if (e >= E) return;
    int s = src[e], d = dst[e];
    int pos = atomicAdd(&cursor[d], 1);
    csr_src[pos] = s;
    csr_w[pos] = dsq[s] * dsq[d];
}

// h = x @ W_emb + b_emb   (K=128, H=64)
__global__ __launch_bounds__(256) void embed_gemm(const float* __restrict__ x,
                                                  const float* __restrict__ W,
                                                  const float* __restrict__ b,
                                                  float* __restrict__ h, int n) {
    __shared__ float Wl[NF * NH];
    for (int i = threadIdx.x; i < NF * NH; i += 256) Wl[i] = W[i];
    __syncthreads();
    int lane = threadIdx.x & 63;
    int wave = threadIdx.x >> 6;
    int row0 = blockIdx.x * 16 + wave * 4;
    float acc[4] = {0.f, 0.f, 0.f, 0.f};
    for (int k = 0; k < NF; ++k) {
        float wk = Wl[k * NH + lane];
#pragma unroll
        for (int r = 0; r < 4; ++r) {
            int row = min(row0 + r, n - 1);
            acc[r] += x[row * NF + k] * wk;
        }
    }
    float bl = b[lane];
#pragma unroll
    for (int r = 0; r < 4; ++r) {
        int row = row0 + r;
        if (row < n) h[row * NH + lane] = acc[r] + bl;
    }
}

// hw = h @ W   (K=64, H=64); self-loop/bias/relu fused into gather
__global__ __launch_bounds__(256) void layer_gemm(const float* __restrict__ h,
                                                  const float* __restrict__ W,
                                                  float* __restrict__ hw, int n) {
    __shared__ float Wl[NH * NH];
    for (int i = threadIdx.x; i < NH * NH; i += 256) Wl[i] = W[i];
    __syncthreads();
    int lane = threadIdx.x & 63;
    int wave = threadIdx.x >> 6;
    int row0 = blockIdx.x * 16 + wave * 4;
    float acc[4] = {0.f, 0.f, 0.f, 0.f};
    for (int k = 0; k < NH; ++k) {
        float wk = Wl[k * NH + lane];
#pragma unroll
        for (int r = 0; r < 4; ++r) {
            int row = min(row0 + r, n - 1);
            acc[r] += h[row * NH + k] * wk;
        }
    }
#pragma unroll
    for (int r = 0; r < 4; ++r) {
        int row = row0 + r;
        if (row < n) hw[row * NH + lane] = acc[r];
    }
}

// wave per dst node: acc = sum_j w_j * hw[src_j] + dsq^2 * hw[node]; relu(acc+b)
__global__ __launch_bounds__(256) void gather_agg(const int* __restrict__ rowptr,
                                                  const int* __restrict__ csr_src,
                                                  const float* __restrict__ csr_w,
                                                  const float* __restrict__ hw,
                                                  const float* __restrict__ dsq,
                                                  const float* __restrict__ b,
                                                  float* __restrict__ outbuf, int n) {
    int node = blockIdx.x * 4 + (threadIdx.x >> 6);
    int lane = threadIdx.x & 63;
    if (node >= n) return;
    int beg = rowptr[node], end = rowptr[node + 1];
    float ds = dsq[node];
    float acc = hw[node * NH + lane] * ds * ds;
    int j = beg;
    for (; j + 3 < end; j += 4) {
        int s0 = csr_src[j], s1 = csr_src[j + 1], s2 = csr_src[j + 2], s3 = csr_src[j + 3];
        float w0 = csr_w[j], w1 = csr_w[j + 1], w2 = csr_w[j + 2], w3 = csr_w[j + 3];
        float v0 = hw[s0 * NH + lane];
        float v1 = hw[s1 * NH + lane];
        float v2 = hw[s2 * NH + lane];
        float v3 = hw[s3 * NH + lane];
        acc += v0 * w0 + v1 * w1 + v2 * w2 + v3 * w3;
    }
    for (; j < end; ++j) {
        acc += hw[csr_src[j] * NH + lane] * csr_w[j];
    }
    acc += b[lane];
    outbuf[node * NH + lane] = fmaxf(acc, 0.f);
}

extern "C" void kernel_launch(void* const* d_in, const int* in_sizes, int n_in,
                              void* d_out, int out_size, void* d_ws, size_t ws_size,
                              hipStream_t stream) {
    const float* x     = (const float*)d_in[0];
    const int*   ei    = (const int*)d_in[1];
    const float* W_emb = (const float*)d_in[2];
    const float* b_emb = (const float*)d_in[3];
    const float* Ws    = (const float*)d_in[4];
    const float* bs    = (const float*)d_in[5];
    float* out = (float*)d_out;

    const int* src = ei;
    const int* dst = ei + NE;

    char* w = (char*)d_ws;
    int*   cnt     = (int*)w;                 w += NN * 4;
    int*   rowptr  = (int*)w;                 w += (NN + 1) * 4;
    int*   cursor  = (int*)w;                 w += NN * 4;
    float* dsq     = (float*)w;               w += NN * 4;
    int*   csr_src = (int*)w;                 w += NE * 4;
    float* csr_w   = (float*)w;               w += NE * 4;
    float* A       = (float*)w;               w += (size_t)NN * NH * 4;
    float* B       = (float*)w;

    // --- CSR build (once per call) ---
    zero_cnt<<<(NN + 255) / 256, 256, 0, stream>>>(cnt, NN);
    count_deg<<<(NE + 255) / 256, 256, 0, stream>>>(dst, cnt, NE);
    compute_dsq<<<(NN + 255) / 256, 256, 0, stream>>>(cnt, dsq, NN);
    scan_rowptr<<<1, SCAN_T, 0, stream>>>(cnt, rowptr, cursor);
    build_csr<<<(NE + 255) / 256, 256, 0, stream>>>(src, dst, dsq, cursor,
                                                    csr_src, csr_w, NE);

    // --- embedding ---
    embed_gemm<<<(NN + 15) / 16, 256, 0, stream>>>(x, W_emb, b_emb, A, NN);

    // --- 3 GCN layers ---
    for (int l = 0; l < 3; ++l) {
        layer_gemm<<<(NN + 15) / 16, 256, 0, stream>>>(A, Ws + l * NH * NH, B, NN);
        float* dbuf = (l == 2) ? out : A;
        gather_agg<<<(NN + 3) / 4, 256, 0, stream>>>(rowptr, csr_src, csr_w, B,
                                                     dsq, bs + l * NH, dbuf, NN);
    }
}

// Round 3
// 726.857 us; speedup vs baseline: 1.9778x; 1.3004x over previous
//
#include <hip/hip_runtime.h>
#include <math.h>

#define NN 100000
#define NE 1600000
#define NF 128
#define NH 64
#define SB 512  // elements per scan block

__global__ __launch_bounds__(256) void zero_cnt(int* cnt, int n) {
    int i = blockIdx.x * 256 + threadIdx.x;
    if (i < n) cnt[i] = 0;
}

__global__ __launch_bounds__(256) void count_deg(const int* __restrict__ dst,
                                                 int* __restrict__ cnt, int E) {
    int e = blockIdx.x * 256 + threadIdx.x;
    if (e < E) atomicAdd(&cnt[dst[e]], 1);
}

__global__ __launch_bounds__(256) void compute_dsq(const int* __restrict__ cnt,
                                                   float* __restrict__ dsq, int n) {
    int i = blockIdx.x * 256 + threadIdx.x;
    if (i < n) dsq[i] = rsqrtf((float)cnt[i] + 1.0f);  // +1 self-loop
}

// phase 1: per-block local exclusive scan (512 elems/block), write block sums
__global__ __launch_bounds__(256) void scan1(const int* __restrict__ cnt,
                                             int* __restrict__ local,
                                             int* __restrict__ blk_sums, int n) {
    __shared__ int s[256];
    int t = threadIdx.x;
    int base = blockIdx.x * SB + t * 2;
    int a = (base < n) ? cnt[base] : 0;
    int b = (base + 1 < n) ? cnt[base + 1] : 0;
    s[t] = a + b;
    __syncthreads();
    for (int off = 1; off < 256; off <<= 1) {
        int v = (t >= off) ? s[t - off] : 0;
        __syncthreads();
        s[t] += v;
        __syncthreads();
    }
    int excl = (t == 0) ? 0 : s[t - 1];
    if (base < n) local[base] = excl;
    if (base + 1 < n) local[base + 1] = excl + a;
    if (t == 255) blk_sums[blockIdx.x] = s[255];
}

// phase 2: single block exclusive-scans the block sums (B <= 256)
__global__ __launch_bounds__(256) void scan2(int* __restrict__ blk_sums, int B) {
    __shared__ int s[256];
    int t = threadIdx.x;
    s[t] = (t < B) ? blk_sums[t] : 0;
    __syncthreads();
    for (int off = 1; off < 256; off <<= 1) {
        int v = (t >= off) ? s[t - off] : 0;
        __syncthreads();
        s[t] += v;
        __syncthreads();
    }
    if (t < B) blk_sums[t] = (t == 0) ? 0 : s[t - 1];
}

// phase 3: add block offsets -> rowptr, cursor
__global__ __launch_bounds__(256) void scan3(const int* __restrict__ local,
                                             const int* __restrict__ blk_sums,
                                             int* __restrict__ rowptr,
                                             int* __restrict__ cursor, int n) {
    int i = blockIdx.x * 256 + threadIdx.x;
    if (i < n) {
        int v = local[i] + blk_sums[i / SB];
        rowptr[i] = v;
        cursor[i] = v;
    }
    if (i == 0) rowptr[n] = NE;
}

__global__ __launch_bounds__(256) void build_csr(const int* __restrict__ src,
                                                 const int* __restrict__ dst,
                                                 const float* __restrict__ dsq,
                                                 int* __restrict__ cursor,
                                                 int* __restrict__ csr_src,
                                                 float* __restrict__ csr_w, int E) {
    int e = blockIdx.x * 256 + threadIdx.x;
    if (e >= E) return;
    int s = src[e], d = dst[e];
    int pos = atomicAdd(&cursor[d], 1);
    csr_src[pos] = s;
    csr_w[pos] = dsq[s] * dsq[d];
}

// h = x @ W_emb + b_emb   (K=128, H=64)
__global__ __launch_bounds__(256) void embed_gemm(const float* __restrict__ x,
                                                  const float* __restrict__ W,
                                                  const float* __restrict__ b,
                                                  float* __restrict__ h, int n) {
    __shared__ float Wl[NF * NH];
    for (int i = threadIdx.x; i < NF * NH; i += 256) Wl[i] = W[i];
    __syncthreads();
    int lane = threadIdx.x & 63;
    int wave = threadIdx.x >> 6;
    int row0 = blockIdx.x * 16 + wave * 4;
    float acc[4] = {0.f, 0.f, 0.f, 0.f};
    for (int k = 0; k < NF; ++k) {
        float wk = Wl[k * NH + lane];
#pragma unroll
        for (int r = 0; r < 4; ++r) {
            int row = min(row0 + r, n - 1);
            acc[r] += x[row * NF + k] * wk;
        }
    }
    float bl = b[lane];
#pragma unroll
    for (int r = 0; r < 4; ++r) {
        int row = row0 + r;
        if (row < n) h[row * NH + lane] = acc[r] + bl;
    }
}

// hw = h @ W   (K=64, H=64); self-loop/bias/relu fused into gather
__global__ __launch_bounds__(256) void layer_gemm(const float* __restrict__ h,
                                                  const float* __restrict__ W,
                                                  float* __restrict__ hw, int n) {
    __shared__ float Wl[NH * NH];
    for (int i = threadIdx.x; i < NH * NH; i += 256) Wl[i] = W[i];
    __syncthreads();
    int lane = threadIdx.x & 63;
    int wave = threadIdx.x >> 6;
    int row0 = blockIdx.x * 16 + wave * 4;
    float acc[4] = {0.f, 0.f, 0.f, 0.f};
    for (int k = 0; k < NH; ++k) {
        float wk = Wl[k * NH + lane];
#pragma unroll
        for (int r = 0; r < 4; ++r) {
            int row = min(row0 + r, n - 1);
            acc[r] += h[row * NH + k] * wk;
        }
    }
#pragma unroll
    for (int r = 0; r < 4; ++r) {
        int row = row0 + r;
        if (row < n) hw[row * NH + lane] = acc[r];
    }
}

// wave per dst node: acc = sum_j w_j * hw[src_j] + dsq^2 * hw[node]; relu(acc+b)
__global__ __launch_bounds__(256) void gather_agg(const int* __restrict__ rowptr,
                                                  const int* __restrict__ csr_src,
                                                  const float* __restrict__ csr_w,
                                                  const float* __restrict__ hw,
                                                  const float* __restrict__ dsq,
                                                  const float* __restrict__ b,
                                                  float* __restrict__ outbuf, int n) {
    int node = blockIdx.x * 4 + (threadIdx.x >> 6);
    int lane = threadIdx.x & 63;
    if (node >= n) return;
    int beg = rowptr[node], end = rowptr[node + 1];
    float ds = dsq[node];
    float acc = hw[node * NH + lane] * ds * ds;
    int j = beg;
    for (; j + 3 < end; j += 4) {
        int s0 = csr_src[j], s1 = csr_src[j + 1], s2 = csr_src[j + 2], s3 = csr_src[j + 3];
        float w0 = csr_w[j], w1 = csr_w[j + 1], w2 = csr_w[j + 2], w3 = csr_w[j + 3];
        float v0 = hw[s0 * NH + lane];
        float v1 = hw[s1 * NH + lane];
        float v2 = hw[s2 * NH + lane];
        float v3 = hw[s3 * NH + lane];
        acc += v0 * w0 + v1 * w1 + v2 * w2 + v3 * w3;
    }
    for (; j < end; ++j) {
        acc += hw[csr_src[j] * NH + lane] * csr_w[j];
    }
    acc += b[lane];
    outbuf[node * NH + lane] = fmaxf(acc, 0.f);
}

extern "C" void kernel_launch(void* const* d_in, const int* in_sizes, int n_in,
                              void* d_out, int out_size, void* d_ws, size_t ws_size,
                              hipStream_t stream) {
    const float* x     = (const float*)d_in[0];
    const int*   ei    = (const int*)d_in[1];
    const float* W_emb = (const float*)d_in[2];
    const float* b_emb = (const float*)d_in[3];
    const float* Ws    = (const float*)d_in[4];
    const float* bs    = (const float*)d_in[5];
    float* out = (float*)d_out;

    const int* src = ei;
    const int* dst = ei + NE;

    const int NSCAN = (NN + SB - 1) / SB;  // 196

    char* w = (char*)d_ws;
    int*   cnt      = (int*)w;                w += NN * 4;
    int*   rowptr   = (int*)w;                w += (NN + 1) * 4;
    int*   cursor   = (int*)w;                w += NN * 4;
    int*   local    = (int*)w;                w += NN * 4;
    int*   blk_sums = (int*)w;                w += 256 * 4;
    float* dsq      = (float*)w;              w += NN * 4;
    int*   csr_src  = (int*)w;                w += NE * 4;
    float* csr_w    = (float*)w;              w += NE * 4;
    float* A        = (float*)w;              w += (size_t)NN * NH * 4;
    float* B        = (float*)w;

    // --- CSR build (once per call) ---
    zero_cnt<<<(NN + 255) / 256, 256, 0, stream>>>(cnt, NN);
    count_deg<<<(NE + 255) / 256, 256, 0, stream>>>(dst, cnt, NE);
    compute_dsq<<<(NN + 255) / 256, 256, 0, stream>>>(cnt, dsq, NN);
    scan1<<<NSCAN, 256, 0, stream>>>(cnt, local, blk_sums, NN);
    scan2<<<1, 256, 0, stream>>>(blk_sums, NSCAN);
    scan3<<<(NN + 255) / 256, 256, 0, stream>>>(local, blk_sums, rowptr, cursor, NN);
    build_csr<<<(NE + 255) / 256, 256, 0, stream>>>(src, dst, dsq, cursor,
                                                    csr_src, csr_w, NE);

    // --- embedding ---
    embed_gemm<<<(NN + 15) / 16, 256, 0, stream>>>(x, W_emb, b_emb, A, NN);

    // --- 3 GCN layers ---
    for (int l = 0; l < 3; ++l) {
        layer_gemm<<<(NN + 15) / 16, 256, 0, stream>>>(A, Ws + l * NH * NH, B, NN);
        float* dbuf = (l == 2) ? out : A;
        gather_agg<<<(NN + 3) / 4, 256, 0, stream>>>(rowptr, csr_src, csr_w, B,
                                                     dsq, bs + l * NH, dbuf, NN);
    }
}

// Round 4
// 574.119 us; speedup vs baseline: 2.5039x; 1.2660x over previous
//
#include <hip/hip_runtime.h>
#include <math.h>

#define NN 100000
#define NE 1600000
#define NF 128
#define NH 64
#define SB 512  // elements per scan block

__global__ __launch_bounds__(256) void zero_cnt(int* cnt, int n) {
    int i = blockIdx.x * 256 + threadIdx.x;
    if (i < n) cnt[i] = 0;
}

__global__ __launch_bounds__(256) void count_deg(const int* __restrict__ dst,
                                                 int* __restrict__ cnt, int E) {
    int e = blockIdx.x * 256 + threadIdx.x;
    if (e < E) atomicAdd(&cnt[dst[e]], 1);
}

__global__ __launch_bounds__(256) void compute_dsq(const int* __restrict__ cnt,
                                                   float* __restrict__ dsq, int n) {
    int i = blockIdx.x * 256 + threadIdx.x;
    if (i < n) dsq[i] = rsqrtf((float)cnt[i] + 1.0f);  // +1 self-loop
}

// phase 1: per-block local exclusive scan (512 elems/block), write block sums
__global__ __launch_bounds__(256) void scan1(const int* __restrict__ cnt,
                                             int* __restrict__ local,
                                             int* __restrict__ blk_sums, int n) {
    __shared__ int s[256];
    int t = threadIdx.x;
    int base = blockIdx.x * SB + t * 2;
    int a = (base < n) ? cnt[base] : 0;
    int b = (base + 1 < n) ? cnt[base + 1] : 0;
    s[t] = a + b;
    __syncthreads();
    for (int off = 1; off < 256; off <<= 1) {
        int v = (t >= off) ? s[t - off] : 0;
        __syncthreads();
        s[t] += v;
        __syncthreads();
    }
    int excl = (t == 0) ? 0 : s[t - 1];
    if (base < n) local[base] = excl;
    if (base + 1 < n) local[base + 1] = excl + a;
    if (t == 255) blk_sums[blockIdx.x] = s[255];
}

// phase 2: single block exclusive-scans the block sums (B <= 256)
__global__ __launch_bounds__(256) void scan2(int* __restrict__ blk_sums, int B) {
    __shared__ int s[256];
    int t = threadIdx.x;
    s[t] = (t < B) ? blk_sums[t] : 0;
    __syncthreads();
    for (int off = 1; off < 256; off <<= 1) {
        int v = (t >= off) ? s[t - off] : 0;
        __syncthreads();
        s[t] += v;
        __syncthreads();
    }
    if (t < B) blk_sums[t] = (t == 0) ? 0 : s[t - 1];
}

// phase 3: add block offsets -> rowptr, cursor
__global__ __launch_bounds__(256) void scan3(const int* __restrict__ local,
                                             const int* __restrict__ blk_sums,
                                             int* __restrict__ rowptr,
                                             int* __restrict__ cursor, int n) {
    int i = blockIdx.x * 256 + threadIdx.x;
    if (i < n) {
        int v = local[i] + blk_sums[i / SB];
        rowptr[i] = v;
        cursor[i] = v;
    }
    if (i == 0) rowptr[n] = NE;
}

// only src index stored; edge weight folded into pre-scaled features
__global__ __launch_bounds__(256) void build_csr(const int* __restrict__ src,
                                                 const int* __restrict__ dst,
                                                 int* __restrict__ cursor,
                                                 int* __restrict__ csr_src, int E) {
    int e = blockIdx.x * 256 + threadIdx.x;
    if (e >= E) return;
    int pos = atomicAdd(&cursor[dst[e]], 1);
    csr_src[pos] = src[e];
}

// h = x @ W_emb + b_emb. K-split: wave w owns k in [32w,32w+32), W-slice in VGPRs,
// x row values via scalar loads (wave-uniform). Cross-wave reduce through LDS.
// grid: NN/16 blocks x 256 threads. Requires NN % 16 == 0.
__global__ __launch_bounds__(256) void embed_gemm(const float* __restrict__ x,
                                                  const float* __restrict__ W,
                                                  const float* __restrict__ b,
                                                  float* __restrict__ h) {
    __shared__ float red[4][16][NH];
    int lane = threadIdx.x & 63;
    int wave = __builtin_amdgcn_readfirstlane(threadIdx.x >> 6);
    int row0 = blockIdx.x * 16;

    float Wreg[32];
#pragma unroll
    for (int kk = 0; kk < 32; ++kk) Wreg[kk] = W[(wave * 32 + kk) * NH + lane];

    const float* xp = x + (size_t)row0 * NF + wave * 32;
    float acc[16];
#pragma unroll
    for (int r = 0; r < 16; ++r) {
        const float4* xr = (const float4*)(xp + (size_t)r * NF);
        float a = 0.f;
#pragma unroll
        for (int q = 0; q < 8; ++q) {
            float4 v = xr[q];
            a += v.x * Wreg[q * 4 + 0];
            a += v.y * Wreg[q * 4 + 1];
            a += v.z * Wreg[q * 4 + 2];
            a += v.w * Wreg[q * 4 + 3];
        }
        acc[r] = a;
    }
#pragma unroll
    for (int r = 0; r < 16; ++r) red[wave][r][lane] = acc[r];
    __syncthreads();
    int t = threadIdx.x;
#pragma unroll
    for (int i = 0; i < 4; ++i) {
        int o = i * 256 + t;
        int r = o >> 6, c = o & 63;
        float s = red[0][r][c] + red[1][r][c] + red[2][r][c] + red[3][r][c];
        h[(size_t)(row0 + r) * NH + c] = s + b[c];
    }
}

// hws = (h @ W) * dsq[row].  K=64 split 4 ways (16 per wave).
__global__ __launch_bounds__(256) void layer_gemm(const float* __restrict__ h,
                                                  const float* __restrict__ W,
                                                  const float* __restrict__ dsq,
                                                  float* __restrict__ hws) {
    __shared__ float red[4][16][NH];
    int lane = threadIdx.x & 63;
    int wave = __builtin_amdgcn_readfirstlane(threadIdx.x >> 6);
    int row0 = blockIdx.x * 16;

    float Wreg[16];
#pragma unroll
    for (int kk = 0; kk < 16; ++kk) Wreg[kk] = W[(wave * 16 + kk) * NH + lane];

    const float* hp = h + (size_t)row0 * NH + wave * 16;
    float acc[16];
#pragma unroll
    for (int r = 0; r < 16; ++r) {
        const float4* hr = (const float4*)(hp + (size_t)r * NH);
        float a = 0.f;
#pragma unroll
        for (int q = 0; q < 4; ++q) {
            float4 v = hr[q];
            a += v.x * Wreg[q * 4 + 0];
            a += v.y * Wreg[q * 4 + 1];
            a += v.z * Wreg[q * 4 + 2];
            a += v.w * Wreg[q * 4 + 3];
        }
        acc[r] = a;
    }
#pragma unroll
    for (int r = 0; r < 16; ++r) red[wave][r][lane] = acc[r];
    __syncthreads();
    int t = threadIdx.x;
#pragma unroll
    for (int i = 0; i < 4; ++i) {
        int o = i * 256 + t;
        int r = o >> 6, c = o & 63;
        float s = red[0][r][c] + red[1][r][c] + red[2][r][c] + red[3][r][c];
        hws[(size_t)(row0 + r) * NH + c] = s * dsq[row0 + r];
    }
}

// wave per dst node: out = relu(dsq[d] * (sum_j hws[src_j] + hws[d]) + b)
__global__ __launch_bounds__(256) void gather_agg(const int* __restrict__ rowptr,
                                                  const int* __restrict__ csr_src,
                                                  const float* __restrict__ hws,
                                                  const float* __restrict__ dsq,
                                                  const float* __restrict__ b,
                                                  float* __restrict__ outbuf, int n) {
    int node = blockIdx.x * 4 + (threadIdx.x >> 6);
    int lane = threadIdx.x & 63;
    if (node >= n) return;
    int beg = rowptr[node], end = rowptr[node + 1];
    float acc = hws[(size_t)node * NH + lane];
    int j = beg;
    for (; j + 3 < end; j += 4) {
        int s0 = csr_src[j], s1 = csr_src[j + 1], s2 = csr_src[j + 2], s3 = csr_src[j + 3];
        float v0 = hws[(size_t)s0 * NH + lane];
        float v1 = hws[(size_t)s1 * NH + lane];
        float v2 = hws[(size_t)s2 * NH + lane];
        float v3 = hws[(size_t)s3 * NH + lane];
        acc += (v0 + v1) + (v2 + v3);
    }
    for (; j < end; ++j) {
        acc += hws[(size_t)csr_src[j] * NH + lane];
    }
    outbuf[(size_t)node * NH + lane] = fmaxf(dsq[node] * acc + b[lane], 0.f);
}

extern "C" void kernel_launch(void* const* d_in, const int* in_sizes, int n_in,
                              void* d_out, int out_size, void* d_ws, size_t ws_size,
                              hipStream_t stream) {
    const float* x     = (const float*)d_in[0];
    const int*   ei    = (const int*)d_in[1];
    const float* W_emb = (const float*)d_in[2];
    const float* b_emb = (const float*)d_in[3];
    const float* Ws    = (const float*)d_in[4];
    const float* bs    = (const float*)d_in[5];
    float* out = (float*)d_out;

    const int* src = ei;
    const int* dst = ei + NE;

    const int NSCAN = (NN + SB - 1) / SB;  // 196

    char* w = (char*)d_ws;
    int*   cnt      = (int*)w;                w += NN * 4;
    int*   rowptr   = (int*)w;                w += (NN + 1) * 4;
    int*   cursor   = (int*)w;                w += NN * 4;
    int*   local    = (int*)w;                w += NN * 4;
    int*   blk_sums = (int*)w;                w += 256 * 4;
    float* dsq      = (float*)w;              w += NN * 4;
    int*   csr_src  = (int*)w;                w += NE * 4;
    float* A        = (float*)w;              w += (size_t)NN * NH * 4;
    float* B        = (float*)w;

    // --- CSR build (once per call) ---
    zero_cnt<<<(NN + 255) / 256, 256, 0, stream>>>(cnt, NN);
    count_deg<<<(NE + 255) / 256, 256, 0, stream>>>(dst, cnt, NE);
    compute_dsq<<<(NN + 255) / 256, 256, 0, stream>>>(cnt, dsq, NN);
    scan1<<<NSCAN, 256, 0, stream>>>(cnt, local, blk_sums, NN);
    scan2<<<1, 256, 0, stream>>>(blk_sums, NSCAN);
    scan3<<<(NN + 255) / 256, 256, 0, stream>>>(local, blk_sums, rowptr, cursor, NN);
    build_csr<<<(NE + 255) / 256, 256, 0, stream>>>(src, dst, cursor, csr_src, NE);

    // --- embedding ---
    embed_gemm<<<NN / 16, 256, 0, stream>>>(x, W_emb, b_emb, A);

    // --- 3 GCN layers ---
    for (int l = 0; l < 3; ++l) {
        layer_gemm<<<NN / 16, 256, 0, stream>>>(A, Ws + l * NH * NH, dsq, B);
        float* dbuf = (l == 2) ? out : A;
        gather_agg<<<(NN + 3) / 4, 256, 0, stream>>>(rowptr, csr_src, B,
                                                     dsq, bs + l * NH, dbuf, NN);
    }
}

// Round 5
// 498.274 us; speedup vs baseline: 2.8850x; 1.1522x over previous
//
#include <hip/hip_runtime.h>
#include <math.h>

#define NN 100000
#define NE 1600000
#define NF 128
#define NH 64
#define SB 512        // elements per scan block
#define NBUCK 196     // ceil(NN / 512)
#define CHA 8192      // edges per block in partition pass

__global__ __launch_bounds__(256) void zero_cnt(int* cnt, int n) {
    int i = blockIdx.x * 256 + threadIdx.x;
    if (i < n) cnt[i] = 0;
}

__global__ __launch_bounds__(256) void count_deg(const int* __restrict__ dst,
                                                 int* __restrict__ cnt, int E) {
    int e = blockIdx.x * 256 + threadIdx.x;
    if (e < E) atomicAdd(&cnt[dst[e]], 1);
}

__global__ __launch_bounds__(256) void compute_dsq(const int* __restrict__ cnt,
                                                   float* __restrict__ dsq, int n) {
    int i = blockIdx.x * 256 + threadIdx.x;
    if (i < n) dsq[i] = rsqrtf((float)cnt[i] + 1.0f);  // +1 self-loop
}

// phase 1: per-block local exclusive scan (512 elems/block), write block sums
__global__ __launch_bounds__(256) void scan1(const int* __restrict__ cnt,
                                             int* __restrict__ local,
                                             int* __restrict__ blk_sums, int n) {
    __shared__ int s[256];
    int t = threadIdx.x;
    int base = blockIdx.x * SB + t * 2;
    int a = (base < n) ? cnt[base] : 0;
    int b = (base + 1 < n) ? cnt[base + 1] : 0;
    s[t] = a + b;
    __syncthreads();
    for (int off = 1; off < 256; off <<= 1) {
        int v = (t >= off) ? s[t - off] : 0;
        __syncthreads();
        s[t] += v;
        __syncthreads();
    }
    int excl = (t == 0) ? 0 : s[t - 1];
    if (base < n) local[base] = excl;
    if (base + 1 < n) local[base + 1] = excl + a;
    if (t == 255) blk_sums[blockIdx.x] = s[255];
}

// phase 2: single block exclusive-scans the block sums (B <= 256)
__global__ __launch_bounds__(256) void scan2(int* __restrict__ blk_sums, int B) {
    __shared__ int s[256];
    int t = threadIdx.x;
    s[t] = (t < B) ? blk_sums[t] : 0;
    __syncthreads();
    for (int off = 1; off < 256; off <<= 1) {
        int v = (t >= off) ? s[t - off] : 0;
        __syncthreads();
        s[t] += v;
        __syncthreads();
    }
    if (t < B) blk_sums[t] = (t == 0) ? 0 : s[t - 1];
}

// phase 3: add block offsets -> rowptr; init bucket cursors from rowptr
__global__ __launch_bounds__(256) void scan3(const int* __restrict__ local,
                                             const int* __restrict__ blk_sums,
                                             int* __restrict__ rowptr,
                                             int* __restrict__ bcur, int n) {
    int i = blockIdx.x * 256 + threadIdx.x;
    if (i < n) {
        int v = local[i] + blk_sums[i / SB];
        rowptr[i] = v;
        if ((i & 511) == 0) bcur[i >> 9] = v;
    }
    if (i == 0) rowptr[n] = NE;
}

// Pass A: partition edges into 512-node dst-buckets. Packed entry:
// (dst & 511) << 17 | src   (src < 2^17). Contiguous runs per (block,bucket).
__global__ __launch_bounds__(256) void part_bucket(const int* __restrict__ src,
                                                   const int* __restrict__ dst,
                                                   int* __restrict__ bcur,
                                                   int* __restrict__ tmp, int E) {
    __shared__ int hist[NBUCK];
    __shared__ int base[NBUCK];
    int t = threadIdx.x;
    int e0 = blockIdx.x * CHA;
    int e1 = min(e0 + CHA, E);
    if (t < NBUCK) hist[t] = 0;
    __syncthreads();
    for (int i = e0 + t; i < e1; i += 256) {
        atomicAdd(&hist[dst[i] >> 9], 1);
    }
    __syncthreads();
    if (t < NBUCK) {
        int h = hist[t];
        base[t] = h ? atomicAdd(&bcur[t], h) : 0;
        hist[t] = 0;
    }
    __syncthreads();
    for (int i = e0 + t; i < e1; i += 256) {
        int d = dst[i];
        int b = d >> 9;
        int r = atomicAdd(&hist[b], 1);
        tmp[base[b] + r] = ((d & 511) << 17) | src[i];
    }
}

// Pass B: one workgroup per bucket; scatter within its own 32KB region using
// LDS per-node cursors. All writes stay in one L2-resident region.
__global__ __launch_bounds__(256) void bucket_scatter(const int* __restrict__ rowptr,
                                                      const int* __restrict__ tmp,
                                                      int* __restrict__ csr_src) {
    __shared__ int cur[512];
    int b = blockIdx.x;
    int t = threadIdx.x;
    int nodelo = b << 9;
    int nnodes = min(512, NN - nodelo);
    int base = rowptr[nodelo];
    int end = rowptr[nodelo + nnodes];
    for (int i = t; i < nnodes; i += 256) cur[i] = rowptr[nodelo + i] - base;
    __syncthreads();
    for (int i = base + t; i < end; i += 256) {
        int e = tmp[i];
        int dlow = e >> 17;
        int s = e & 0x1FFFF;
        int p = atomicAdd(&cur[dlow], 1);
        csr_src[base + p] = s;
    }
}

// h = x @ W_emb + b_emb. K-split: wave w owns k in [32w,32w+32), W-slice in VGPRs.
__global__ __launch_bounds__(256) void embed_gemm(const float* __restrict__ x,
                                                  const float* __restrict__ W,
                                                  const float* __restrict__ b,
                                                  float* __restrict__ h) {
    __shared__ float red[4][16][NH];
    int lane = threadIdx.x & 63;
    int wave = __builtin_amdgcn_readfirstlane(threadIdx.x >> 6);
    int row0 = blockIdx.x * 16;

    float Wreg[32];
#pragma unroll
    for (int kk = 0; kk < 32; ++kk) Wreg[kk] = W[(wave * 32 + kk) * NH + lane];

    const float* xp = x + (size_t)row0 * NF + wave * 32;
    float acc[16];
#pragma unroll
    for (int r = 0; r < 16; ++r) {
        const float4* xr = (const float4*)(xp + (size_t)r * NF);
        float a = 0.f;
#pragma unroll
        for (int q = 0; q < 8; ++q) {
            float4 v = xr[q];
            a += v.x * Wreg[q * 4 + 0];
            a += v.y * Wreg[q * 4 + 1];
            a += v.z * Wreg[q * 4 + 2];
            a += v.w * Wreg[q * 4 + 3];
        }
        acc[r] = a;
    }
#pragma unroll
    for (int r = 0; r < 16; ++r) red[wave][r][lane] = acc[r];
    __syncthreads();
    int t = threadIdx.x;
#pragma unroll
    for (int i = 0; i < 4; ++i) {
        int o = i * 256 + t;
        int r = o >> 6, c = o & 63;
        float s = red[0][r][c] + red[1][r][c] + red[2][r][c] + red[3][r][c];
        h[(size_t)(row0 + r) * NH + c] = s + b[c];
    }
}

// hws = (h @ W) * dsq[row].  K=64 split 4 ways (16 per wave).
__global__ __launch_bounds__(256) void layer_gemm(const float* __restrict__ h,
                                                  const float* __restrict__ W,
                                                  const float* __restrict__ dsq,
                                                  float* __restrict__ hws) {
    __shared__ float red[4][16][NH];
    int lane = threadIdx.x & 63;
    int wave = __builtin_amdgcn_readfirstlane(threadIdx.x >> 6);
    int row0 = blockIdx.x * 16;

    float Wreg[16];
#pragma unroll
    for (int kk = 0; kk < 16; ++kk) Wreg[kk] = W[(wave * 16 + kk) * NH + lane];

    const float* hp = h + (size_t)row0 * NH + wave * 16;
    float acc[16];
#pragma unroll
    for (int r = 0; r < 16; ++r) {
        const float4* hr = (const float4*)(hp + (size_t)r * NH);
        float a = 0.f;
#pragma unroll
        for (int q = 0; q < 4; ++q) {
            float4 v = hr[q];
            a += v.x * Wreg[q * 4 + 0];
            a += v.y * Wreg[q * 4 + 1];
            a += v.z * Wreg[q * 4 + 2];
            a += v.w * Wreg[q * 4 + 3];
        }
        acc[r] = a;
    }
#pragma unroll
    for (int r = 0; r < 16; ++r) red[wave][r][lane] = acc[r];
    __syncthreads();
    int t = threadIdx.x;
#pragma unroll
    for (int i = 0; i < 4; ++i) {
        int o = i * 256 + t;
        int r = o >> 6, c = o & 63;
        float s = red[0][r][c] + red[1][r][c] + red[2][r][c] + red[3][r][c];
        hws[(size_t)(row0 + r) * NH + c] = s * dsq[row0 + r];
    }
}

// wave per dst node: out = relu(dsq[d] * (sum_j hws[src_j] + hws[d]) + b)
__global__ __launch_bounds__(256) void gather_agg(const int* __restrict__ rowptr,
                                                  const int* __restrict__ csr_src,
                                                  const float* __restrict__ hws,
                                                  const float* __restrict__ dsq,
                                                  const float* __restrict__ b,
                                                  float* __restrict__ outbuf, int n) {
    int node = blockIdx.x * 4 + (threadIdx.x >> 6);
    int lane = threadIdx.x & 63;
    if (node >= n) return;
    int beg = rowptr[node], end = rowptr[node + 1];
    float acc = hws[(size_t)node * NH + lane];
    int j = beg;
    for (; j + 3 < end; j += 4) {
        int s0 = csr_src[j], s1 = csr_src[j + 1], s2 = csr_src[j + 2], s3 = csr_src[j + 3];
        float v0 = hws[(size_t)s0 * NH + lane];
        float v1 = hws[(size_t)s1 * NH + lane];
        float v2 = hws[(size_t)s2 * NH + lane];
        float v3 = hws[(size_t)s3 * NH + lane];
        acc += (v0 + v1) + (v2 + v3);
    }
    for (; j < end; ++j) {
        acc += hws[(size_t)csr_src[j] * NH + lane];
    }
    outbuf[(size_t)node * NH + lane] = fmaxf(dsq[node] * acc + b[lane], 0.f);
}

extern "C" void kernel_launch(void* const* d_in, const int* in_sizes, int n_in,
                              void* d_out, int out_size, void* d_ws, size_t ws_size,
                              hipStream_t stream) {
    const float* x     = (const float*)d_in[0];
    const int*   ei    = (const int*)d_in[1];
    const float* W_emb = (const float*)d_in[2];
    const float* b_emb = (const float*)d_in[3];
    const float* Ws    = (const float*)d_in[4];
    const float* bs    = (const float*)d_in[5];
    float* out = (float*)d_out;

    const int* src = ei;
    const int* dst = ei + NE;

    const int NSCAN = (NN + SB - 1) / SB;  // 196

    char* w = (char*)d_ws;
    int*   cnt      = (int*)w;                w += NN * 4;
    int*   rowptr   = (int*)w;                w += (NN + 1) * 4;
    int*   local    = (int*)w;                w += NN * 4;
    int*   blk_sums = (int*)w;                w += 256 * 4;
    int*   bcur     = (int*)w;                w += 256 * 4;
    float* dsq      = (float*)w;              w += NN * 4;
    int*   csr_src  = (int*)w;                w += NE * 4;
    int*   tmp      = (int*)w;                w += (size_t)NE * 4;
    float* A        = (float*)w;              w += (size_t)NN * NH * 4;
    float* B        = (float*)w;

    // --- CSR build (once per call) ---
    zero_cnt<<<(NN + 255) / 256, 256, 0, stream>>>(cnt, NN);
    count_deg<<<(NE + 255) / 256, 256, 0, stream>>>(dst, cnt, NE);
    compute_dsq<<<(NN + 255) / 256, 256, 0, stream>>>(cnt, dsq, NN);
    scan1<<<NSCAN, 256, 0, stream>>>(cnt, local, blk_sums, NN);
    scan2<<<1, 256, 0, stream>>>(blk_sums, NSCAN);
    scan3<<<(NN + 255) / 256, 256, 0, stream>>>(local, blk_sums, rowptr, bcur, NN);
    part_bucket<<<(NE + CHA - 1) / CHA, 256, 0, stream>>>(src, dst, bcur, tmp, NE);
    bucket_scatter<<<NBUCK, 256, 0, stream>>>(rowptr, tmp, csr_src);

    // --- embedding ---
    embed_gemm<<<NN / 16, 256, 0, stream>>>(x, W_emb, b_emb, A);

    // --- 3 GCN layers ---
    for (int l = 0; l < 3; ++l) {
        layer_gemm<<<NN / 16, 256, 0, stream>>>(A, Ws + l * NH * NH, dsq, B);
        float* dbuf = (l == 2) ? out : A;
        gather_agg<<<(NN + 3) / 4, 256, 0, stream>>>(rowptr, csr_src, B,
                                                     dsq, bs + l * NH, dbuf, NN);
    }
}

// Round 6
// 421.511 us; speedup vs baseline: 3.4105x; 1.1821x over previous
//
#include <hip/hip_runtime.h>
#include <hip/hip_fp16.h>
#include <math.h>

#define NN 100000
#define NE 1600000
#define NF 128
#define NH 64
#define SB 512        // elements per scan block
#define NBUCK 196     // ceil(NN / 512)
#define CHA 8192      // edges per block in partition pass

__global__ __launch_bounds__(256) void zero_cnt(int* cnt, int n) {
    int i = blockIdx.x * 256 + threadIdx.x;
    if (i < n) cnt[i] = 0;
}

__global__ __launch_bounds__(256) void count_deg(const int* __restrict__ dst,
                                                 int* __restrict__ cnt, int E) {
    int e = blockIdx.x * 256 + threadIdx.x;
    if (e < E) atomicAdd(&cnt[dst[e]], 1);
}

__global__ __launch_bounds__(256) void compute_dsq(const int* __restrict__ cnt,
                                                   float* __restrict__ dsq, int n) {
    int i = blockIdx.x * 256 + threadIdx.x;
    if (i < n) dsq[i] = rsqrtf((float)cnt[i] + 1.0f);  // +1 self-loop
}

// phase 1: per-block local exclusive scan (512 elems/block), write block sums
__global__ __launch_bounds__(256) void scan1(const int* __restrict__ cnt,
                                             int* __restrict__ local,
                                             int* __restrict__ blk_sums, int n) {
    __shared__ int s[256];
    int t = threadIdx.x;
    int base = blockIdx.x * SB + t * 2;
    int a = (base < n) ? cnt[base] : 0;
    int b = (base + 1 < n) ? cnt[base + 1] : 0;
    s[t] = a + b;
    __syncthreads();
    for (int off = 1; off < 256; off <<= 1) {
        int v = (t >= off) ? s[t - off] : 0;
        __syncthreads();
        s[t] += v;
        __syncthreads();
    }
    int excl = (t == 0) ? 0 : s[t - 1];
    if (base < n) local[base] = excl;
    if (base + 1 < n) local[base + 1] = excl + a;
    if (t == 255) blk_sums[blockIdx.x] = s[255];
}

// phase 2: single block exclusive-scans the block sums (B <= 256)
__global__ __launch_bounds__(256) void scan2(int* __restrict__ blk_sums, int B) {
    __shared__ int s[256];
    int t = threadIdx.x;
    s[t] = (t < B) ? blk_sums[t] : 0;
    __syncthreads();
    for (int off = 1; off < 256; off <<= 1) {
        int v = (t >= off) ? s[t - off] : 0;
        __syncthreads();
        s[t] += v;
        __syncthreads();
    }
    if (t < B) blk_sums[t] = (t == 0) ? 0 : s[t - 1];
}

// phase 3: add block offsets -> rowptr; init bucket cursors from rowptr
__global__ __launch_bounds__(256) void scan3(const int* __restrict__ local,
                                             const int* __restrict__ blk_sums,
                                             int* __restrict__ rowptr,
                                             int* __restrict__ bcur, int n) {
    int i = blockIdx.x * 256 + threadIdx.x;
    if (i < n) {
        int v = local[i] + blk_sums[i / SB];
        rowptr[i] = v;
        if ((i & 511) == 0) bcur[i >> 9] = v;
    }
    if (i == 0) rowptr[n] = NE;
}

// Pass A: partition edges into 512-node dst-buckets. Packed entry:
// (dst & 511) << 17 | src   (src < 2^17). Contiguous runs per (block,bucket).
__global__ __launch_bounds__(256) void part_bucket(const int* __restrict__ src,
                                                   const int* __restrict__ dst,
                                                   int* __restrict__ bcur,
                                                   int* __restrict__ tmp, int E) {
    __shared__ int hist[NBUCK];
    __shared__ int base[NBUCK];
    int t = threadIdx.x;
    int e0 = blockIdx.x * CHA;
    int e1 = min(e0 + CHA, E);
    if (t < NBUCK) hist[t] = 0;
    __syncthreads();
    for (int i = e0 + t; i < e1; i += 256) {
        atomicAdd(&hist[dst[i] >> 9], 1);
    }
    __syncthreads();
    if (t < NBUCK) {
        int h = hist[t];
        base[t] = h ? atomicAdd(&bcur[t], h) : 0;
        hist[t] = 0;
    }
    __syncthreads();
    for (int i = e0 + t; i < e1; i += 256) {
        int d = dst[i];
        int b = d >> 9;
        int r = atomicAdd(&hist[b], 1);
        tmp[base[b] + r] = ((d & 511) << 17) | src[i];
    }
}

// Pass B: one workgroup per bucket; scatter within its own 32KB region using
// LDS per-node cursors. All writes stay in one L2-resident region.
__global__ __launch_bounds__(256) void bucket_scatter(const int* __restrict__ rowptr,
                                                      const int* __restrict__ tmp,
                                                      int* __restrict__ csr_src) {
    __shared__ int cur[512];
    int b = blockIdx.x;
    int t = threadIdx.x;
    int nodelo = b << 9;
    int nnodes = min(512, NN - nodelo);
    int base = rowptr[nodelo];
    int end = rowptr[nodelo + nnodes];
    for (int i = t; i < nnodes; i += 256) cur[i] = rowptr[nodelo + i] - base;
    __syncthreads();
    for (int i = base + t; i < end; i += 256) {
        int e = tmp[i];
        int dlow = e >> 17;
        int s = e & 0x1FFFF;
        int p = atomicAdd(&cur[dlow], 1);
        csr_src[base + p] = s;
    }
}

// Wc = We @ W0  [128x64], bc = be @ W0 [64]  (fold embed into layer-0 GEMM)
__global__ __launch_bounds__(256) void combine_w(const float* __restrict__ We,
                                                 const float* __restrict__ be,
                                                 const float* __restrict__ W0,
                                                 float* __restrict__ Wc,
                                                 float* __restrict__ bc) {
    __shared__ float w0[NH * NH];
    int t = threadIdx.x;
    for (int i = t; i < NH * NH; i += 256) w0[i] = W0[i];
    __syncthreads();
    int row = blockIdx.x * 4 + (t >> 6);  // We row, grid = 32
    int col = t & 63;
    float a = 0.f;
#pragma unroll 8
    for (int k = 0; k < NH; ++k) a += We[row * NH + k] * w0[k * NH + col];
    Wc[row * NH + col] = a;
    if (blockIdx.x == 0 && t < NH) {
        float s = 0.f;
        for (int k = 0; k < NH; ++k) s += be[k] * w0[k * NH + t];
        bc[t] = s;
    }
}

// hws0 = (x @ Wc + bc) * dsq[row], fp16 out.  K=128, LDS-staged x tile.
// block 256 = 4 waves, 16 rows/block, k-split 32/wave. grid NN/16.
__global__ __launch_bounds__(256) void fuse0_gemm(const float* __restrict__ x,
                                                  const float* __restrict__ Wc,
                                                  const float* __restrict__ bc,
                                                  const float* __restrict__ dsq,
                                                  __half* __restrict__ hws) {
    __shared__ float tile[16 * NF];          // 8 KB
    __shared__ float red[4][16][NH];         // 16 KB
    int t = threadIdx.x;
    int lane = t & 63;
    int wave = __builtin_amdgcn_readfirstlane(t >> 6);
    int row0 = blockIdx.x * 16;

    // coalesced stage: 2048 floats = 512 float4, 2 per thread
    const float4* xsrc = (const float4*)(x + (size_t)row0 * NF);
    float4* t4 = (float4*)tile;
    t4[t] = xsrc[t];
    t4[t + 256] = xsrc[t + 256];

    float Wreg[32];
#pragma unroll
    for (int kk = 0; kk < 32; ++kk) Wreg[kk] = Wc[(wave * 32 + kk) * NH + lane];
    __syncthreads();

    float acc[16];
#pragma unroll
    for (int r = 0; r < 16; ++r) {
        const float4* rp = (const float4*)(tile + r * NF + wave * 32);
        float a = 0.f;
#pragma unroll
        for (int q = 0; q < 8; ++q) {
            float4 v = rp[q];
            a += v.x * Wreg[q * 4 + 0];
            a += v.y * Wreg[q * 4 + 1];
            a += v.z * Wreg[q * 4 + 2];
            a += v.w * Wreg[q * 4 + 3];
        }
        acc[r] = a;
    }
#pragma unroll
    for (int r = 0; r < 16; ++r) red[wave][r][lane] = acc[r];
    __syncthreads();
#pragma unroll
    for (int i = 0; i < 4; ++i) {
        int o = i * 256 + t;
        int r = o >> 6, c = o & 63;
        float s = red[0][r][c] + red[1][r][c] + red[2][r][c] + red[3][r][c];
        int row = row0 + r;
        hws[(size_t)row * NH + c] = __float2half((s + bc[c]) * dsq[row]);
    }
}

// hws = (h @ W) * dsq[row], fp16 out.  K=64, LDS-staged h tile.
__global__ __launch_bounds__(256) void layer_gemm(const float* __restrict__ h,
                                                  const float* __restrict__ W,
                                                  const float* __restrict__ dsq,
                                                  __half* __restrict__ hws) {
    __shared__ float tile[16 * NH];          // 4 KB
    __shared__ float red[4][16][NH];         // 16 KB
    int t = threadIdx.x;
    int lane = t & 63;
    int wave = __builtin_amdgcn_readfirstlane(t >> 6);
    int row0 = blockIdx.x * 16;

    const float4* hsrc = (const float4*)(h + (size_t)row0 * NH);
    float4* t4 = (float4*)tile;
    t4[t] = hsrc[t];

    float Wreg[16];
#pragma unroll
    for (int kk = 0; kk < 16; ++kk) Wreg[kk] = W[(wave * 16 + kk) * NH + lane];
    __syncthreads();

    float acc[16];
#pragma unroll
    for (int r = 0; r < 16; ++r) {
        const float4* rp = (const float4*)(tile + r * NH + wave * 16);
        float a = 0.f;
#pragma unroll
        for (int q = 0; q < 4; ++q) {
            float4 v = rp[q];
            a += v.x * Wreg[q * 4 + 0];
            a += v.y * Wreg[q * 4 + 1];
            a += v.z * Wreg[q * 4 + 2];
            a += v.w * Wreg[q * 4 + 3];
        }
        acc[r] = a;
    }
#pragma unroll
    for (int r = 0; r < 16; ++r) red[wave][r][lane] = acc[r];
    __syncthreads();
#pragma unroll
    for (int i = 0; i < 4; ++i) {
        int o = i * 256 + t;
        int r = o >> 6, c = o & 63;
        float s = red[0][r][c] + red[1][r][c] + red[2][r][c] + red[3][r][c];
        int row = row0 + r;
        hws[(size_t)row * NH + c] = __float2half(s * dsq[row]);
    }
}

// wave per dst node: out = relu(dsq[d] * (sum_j hws[src_j] + hws[d]) + b)
// hws is fp16 (128 B/row); accumulate fp32.
__global__ __launch_bounds__(256) void gather_agg(const int* __restrict__ rowptr,
                                                  const int* __restrict__ csr_src,
                                                  const __half* __restrict__ hws,
                                                  const float* __restrict__ dsq,
                                                  const float* __restrict__ b,
                                                  float* __restrict__ outbuf, int n) {
    int node = blockIdx.x * 4 + (threadIdx.x >> 6);
    int lane = threadIdx.x & 63;
    if (node >= n) return;
    int beg = rowptr[node], end = rowptr[node + 1];
    float acc = __half2float(hws[(size_t)node * NH + lane]);
    int j = beg;
    for (; j + 7 < end; j += 8) {
        int s0 = csr_src[j], s1 = csr_src[j + 1], s2 = csr_src[j + 2], s3 = csr_src[j + 3];
        int s4 = csr_src[j + 4], s5 = csr_src[j + 5], s6 = csr_src[j + 6], s7 = csr_src[j + 7];
        float v0 = __half2float(hws[(size_t)s0 * NH + lane]);
        float v1 = __half2float(hws[(size_t)s1 * NH + lane]);
        float v2 = __half2float(hws[(size_t)s2 * NH + lane]);
        float v3 = __half2float(hws[(size_t)s3 * NH + lane]);
        float v4 = __half2float(hws[(size_t)s4 * NH + lane]);
        float v5 = __half2float(hws[(size_t)s5 * NH + lane]);
        float v6 = __half2float(hws[(size_t)s6 * NH + lane]);
        float v7 = __half2float(hws[(size_t)s7 * NH + lane]);
        acc += ((v0 + v1) + (v2 + v3)) + ((v4 + v5) + (v6 + v7));
    }
    for (; j < end; ++j) {
        acc += __half2float(hws[(size_t)csr_src[j] * NH + lane]);
    }
    outbuf[(size_t)node * NH + lane] = fmaxf(dsq[node] * acc + b[lane], 0.f);
}

extern "C" void kernel_launch(void* const* d_in, const int* in_sizes, int n_in,
                              void* d_out, int out_size, void* d_ws, size_t ws_size,
                              hipStream_t stream) {
    const float* x     = (const float*)d_in[0];
    const int*   ei    = (const int*)d_in[1];
    const float* W_emb = (const float*)d_in[2];
    const float* b_emb = (const float*)d_in[3];
    const float* Ws    = (const float*)d_in[4];
    const float* bs    = (const float*)d_in[5];
    float* out = (float*)d_out;

    const int* src = ei;
    const int* dst = ei + NE;

    const int NSCAN = (NN + SB - 1) / SB;  // 196

    char* w = (char*)d_ws;
    int*    cnt      = (int*)w;               w += NN * 4;
    int*    rowptr   = (int*)w;               w += (NN + 1) * 4;
    int*    local    = (int*)w;               w += NN * 4;
    int*    blk_sums = (int*)w;               w += 256 * 4;
    int*    bcur     = (int*)w;               w += 256 * 4;
    float*  dsq      = (float*)w;             w += NN * 4;
    float*  Wc       = (float*)w;             w += NF * NH * 4;
    float*  bc       = (float*)w;             w += NH * 4;
    int*    csr_src  = (int*)w;               w += NE * 4;
    int*    tmp      = (int*)w;               w += (size_t)NE * 4;
    float*  A        = (float*)w;             w += (size_t)NN * NH * 4;
    __half* Bh       = (__half*)w;

    // --- CSR build (once per call) ---
    zero_cnt<<<(NN + 255) / 256, 256, 0, stream>>>(cnt, NN);
    count_deg<<<(NE + 255) / 256, 256, 0, stream>>>(dst, cnt, NE);
    compute_dsq<<<(NN + 255) / 256, 256, 0, stream>>>(cnt, dsq, NN);
    scan1<<<NSCAN, 256, 0, stream>>>(cnt, local, blk_sums, NN);
    scan2<<<1, 256, 0, stream>>>(blk_sums, NSCAN);
    scan3<<<(NN + 255) / 256, 256, 0, stream>>>(local, blk_sums, rowptr, bcur, NN);
    part_bucket<<<(NE + CHA - 1) / CHA, 256, 0, stream>>>(src, dst, bcur, tmp, NE);
    bucket_scatter<<<NBUCK, 256, 0, stream>>>(rowptr, tmp, csr_src);

    // --- fold embed into layer-0 weights ---
    combine_w<<<NF / 4, 256, 0, stream>>>(W_emb, b_emb, Ws, Wc, bc);

    // --- layer 0 (fused with embedding) ---
    fuse0_gemm<<<NN / 16, 256, 0, stream>>>(x, Wc, bc, dsq, Bh);
    gather_agg<<<(NN + 3) / 4, 256, 0, stream>>>(rowptr, csr_src, Bh,
                                                 dsq, bs, A, NN);

    // --- layers 1,2 ---
    for (int l = 1; l < 3; ++l) {
        layer_gemm<<<NN / 16, 256, 0, stream>>>(A, Ws + l * NH * NH, dsq, Bh);
        float* dbuf = (l == 2) ? out : A;
        gather_agg<<<(NN + 3) / 4, 256, 0, stream>>>(rowptr, csr_src, Bh,
                                                     dsq, bs + l * NH, dbuf, NN);
    }
}

// Round 7
// 377.878 us; speedup vs baseline: 3.8043x; 1.1155x over previous
//
#include <hip/hip_runtime.h>
#include <hip/hip_fp16.h>
#include <math.h>

#define NN 100000
#define NE 1600000
#define NF 128
#define NH 64
#define SB 512        // elements per scan block
#define NBUCK 196     // ceil(NN / 512)
#define CHA 8192      // edges per block in partition pass

__global__ __launch_bounds__(256) void zero_cnt(int* cnt, int n) {
    int i = blockIdx.x * 256 + threadIdx.x;
    if (i < n) cnt[i] = 0;
}

__global__ __launch_bounds__(256) void count_deg(const int* __restrict__ dst,
                                                 int* __restrict__ cnt, int E) {
    int e = blockIdx.x * 256 + threadIdx.x;
    if (e < E) atomicAdd(&cnt[dst[e]], 1);
}

__global__ __launch_bounds__(256) void compute_dsq(const int* __restrict__ cnt,
                                                   float* __restrict__ dsq, int n) {
    int i = blockIdx.x * 256 + threadIdx.x;
    if (i < n) dsq[i] = rsqrtf((float)cnt[i] + 1.0f);  // +1 self-loop
}

// phase 1: per-block local exclusive scan (512 elems/block), write block sums
__global__ __launch_bounds__(256) void scan1(const int* __restrict__ cnt,
                                             int* __restrict__ local,
                                             int* __restrict__ blk_sums, int n) {
    __shared__ int s[256];
    int t = threadIdx.x;
    int base = blockIdx.x * SB + t * 2;
    int a = (base < n) ? cnt[base] : 0;
    int b = (base + 1 < n) ? cnt[base + 1] : 0;
    s[t] = a + b;
    __syncthreads();
    for (int off = 1; off < 256; off <<= 1) {
        int v = (t >= off) ? s[t - off] : 0;
        __syncthreads();
        s[t] += v;
        __syncthreads();
    }
    int excl = (t == 0) ? 0 : s[t - 1];
    if (base < n) local[base] = excl;
    if (base + 1 < n) local[base + 1] = excl + a;
    if (t == 255) blk_sums[blockIdx.x] = s[255];
}

// phase 2: single block exclusive-scans the block sums (B <= 256)
__global__ __launch_bounds__(256) void scan2(int* __restrict__ blk_sums, int B) {
    __shared__ int s[256];
    int t = threadIdx.x;
    s[t] = (t < B) ? blk_sums[t] : 0;
    __syncthreads();
    for (int off = 1; off < 256; off <<= 1) {
        int v = (t >= off) ? s[t - off] : 0;
        __syncthreads();
        s[t] += v;
        __syncthreads();
    }
    if (t < B) blk_sums[t] = (t == 0) ? 0 : s[t - 1];
}

// phase 3: add block offsets -> rowptr; init bucket cursors from rowptr
__global__ __launch_bounds__(256) void scan3(const int* __restrict__ local,
                                             const int* __restrict__ blk_sums,
                                             int* __restrict__ rowptr,
                                             int* __restrict__ bcur, int n) {
    int i = blockIdx.x * 256 + threadIdx.x;
    if (i < n) {
        int v = local[i] + blk_sums[i / SB];
        rowptr[i] = v;
        if ((i & 511) == 0) bcur[i >> 9] = v;
    }
    if (i == 0) rowptr[n] = NE;
}

// Pass A: partition edges into 512-node dst-buckets. Packed entry:
// (dst & 511) << 17 | src   (src < 2^17). Contiguous runs per (block,bucket).
__global__ __launch_bounds__(256) void part_bucket(const int* __restrict__ src,
                                                   const int* __restrict__ dst,
                                                   int* __restrict__ bcur,
                                                   int* __restrict__ tmp, int E) {
    __shared__ int hist[NBUCK];
    __shared__ int base[NBUCK];
    int t = threadIdx.x;
    int e0 = blockIdx.x * CHA;
    int e1 = min(e0 + CHA, E);
    if (t < NBUCK) hist[t] = 0;
    __syncthreads();
    for (int i = e0 + t; i < e1; i += 256) {
        atomicAdd(&hist[dst[i] >> 9], 1);
    }
    __syncthreads();
    if (t < NBUCK) {
        int h = hist[t];
        base[t] = h ? atomicAdd(&bcur[t], h) : 0;
        hist[t] = 0;
    }
    __syncthreads();
    for (int i = e0 + t; i < e1; i += 256) {
        int d = dst[i];
        int b = d >> 9;
        int r = atomicAdd(&hist[b], 1);
        tmp[base[b] + r] = ((d & 511) << 17) | src[i];
    }
}

// Pass B: one workgroup per bucket; scatter within its own 32KB region using
// LDS per-node cursors. All writes stay in one L2-resident region.
__global__ __launch_bounds__(256) void bucket_scatter(const int* __restrict__ rowptr,
                                                      const int* __restrict__ tmp,
                                                      int* __restrict__ csr_src) {
    __shared__ int cur[512];
    int b = blockIdx.x;
    int t = threadIdx.x;
    int nodelo = b << 9;
    int nnodes = min(512, NN - nodelo);
    int base = rowptr[nodelo];
    int end = rowptr[nodelo + nnodes];
    for (int i = t; i < nnodes; i += 256) cur[i] = rowptr[nodelo + i] - base;
    __syncthreads();
    for (int i = base + t; i < end; i += 256) {
        int e = tmp[i];
        int dlow = e >> 17;
        int s = e & 0x1FFFF;
        int p = atomicAdd(&cur[dlow], 1);
        csr_src[base + p] = s;
    }
}

// Wc = We @ W0  [128x64], bc = be @ W0 [64]  (fold embed into layer-0 GEMM)
__global__ __launch_bounds__(256) void combine_w(const float* __restrict__ We,
                                                 const float* __restrict__ be,
                                                 const float* __restrict__ W0,
                                                 float* __restrict__ Wc,
                                                 float* __restrict__ bc) {
    __shared__ float w0[NH * NH];
    int t = threadIdx.x;
    for (int i = t; i < NH * NH; i += 256) w0[i] = W0[i];
    __syncthreads();
    int row = blockIdx.x * 4 + (t >> 6);  // We row, grid = 32
    int col = t & 63;
    float a = 0.f;
#pragma unroll 8
    for (int k = 0; k < NH; ++k) a += We[row * NH + k] * w0[k * NH + col];
    Wc[row * NH + col] = a;
    if (blockIdx.x == 0 && t < NH) {
        float s = 0.f;
        for (int k = 0; k < NH; ++k) s += be[k] * w0[k * NH + t];
        bc[t] = s;
    }
}

// hws0 = (x @ Wc + bc) * dsq[row], fp16 out.  K=128, LDS-staged x tile.
__global__ __launch_bounds__(256) void fuse0_gemm(const float* __restrict__ x,
                                                  const float* __restrict__ Wc,
                                                  const float* __restrict__ bc,
                                                  const float* __restrict__ dsq,
                                                  __half* __restrict__ hws) {
    __shared__ float tile[16 * NF];          // 8 KB
    __shared__ float red[4][16][NH];         // 16 KB
    int t = threadIdx.x;
    int lane = t & 63;
    int wave = __builtin_amdgcn_readfirstlane(t >> 6);
    int row0 = blockIdx.x * 16;

    const float4* xsrc = (const float4*)(x + (size_t)row0 * NF);
    float4* t4 = (float4*)tile;
    t4[t] = xsrc[t];
    t4[t + 256] = xsrc[t + 256];

    float Wreg[32];
#pragma unroll
    for (int kk = 0; kk < 32; ++kk) Wreg[kk] = Wc[(wave * 32 + kk) * NH + lane];
    __syncthreads();

    float acc[16];
#pragma unroll
    for (int r = 0; r < 16; ++r) {
        const float4* rp = (const float4*)(tile + r * NF + wave * 32);
        float a = 0.f;
#pragma unroll
        for (int q = 0; q < 8; ++q) {
            float4 v = rp[q];
            a += v.x * Wreg[q * 4 + 0];
            a += v.y * Wreg[q * 4 + 1];
            a += v.z * Wreg[q * 4 + 2];
            a += v.w * Wreg[q * 4 + 3];
        }
        acc[r] = a;
    }
#pragma unroll
    for (int r = 0; r < 16; ++r) red[wave][r][lane] = acc[r];
    __syncthreads();
#pragma unroll
    for (int i = 0; i < 4; ++i) {
        int o = i * 256 + t;
        int r = o >> 6, c = o & 63;
        float s = red[0][r][c] + red[1][r][c] + red[2][r][c] + red[3][r][c];
        int row = row0 + r;
        hws[(size_t)row * NH + c] = __float2half((s + bc[c]) * dsq[row]);
    }
}

// hws = (h @ W) * dsq[row], fp16 out.  K=64, LDS-staged h tile.
__global__ __launch_bounds__(256) void layer_gemm(const float* __restrict__ h,
                                                  const float* __restrict__ W,
                                                  const float* __restrict__ dsq,
                                                  __half* __restrict__ hws) {
    __shared__ float tile[16 * NH];          // 4 KB
    __shared__ float red[4][16][NH];         // 16 KB
    int t = threadIdx.x;
    int lane = t & 63;
    int wave = __builtin_amdgcn_readfirstlane(t >> 6);
    int row0 = blockIdx.x * 16;

    const float4* hsrc = (const float4*)(h + (size_t)row0 * NH);
    float4* t4 = (float4*)tile;
    t4[t] = hsrc[t];

    float Wreg[16];
#pragma unroll
    for (int kk = 0; kk < 16; ++kk) Wreg[kk] = W[(wave * 16 + kk) * NH + lane];
    __syncthreads();

    float acc[16];
#pragma unroll
    for (int r = 0; r < 16; ++r) {
        const float4* rp = (const float4*)(tile + r * NH + wave * 16);
        float a = 0.f;
#pragma unroll
        for (int q = 0; q < 4; ++q) {
            float4 v = rp[q];
            a += v.x * Wreg[q * 4 + 0];
            a += v.y * Wreg[q * 4 + 1];
            a += v.z * Wreg[q * 4 + 2];
            a += v.w * Wreg[q * 4 + 3];
        }
        acc[r] = a;
    }
#pragma unroll
    for (int r = 0; r < 16; ++r) red[wave][r][lane] = acc[r];
    __syncthreads();
#pragma unroll
    for (int i = 0; i < 4; ++i) {
        int o = i * 256 + t;
        int r = o >> 6, c = o & 63;
        float s = red[0][r][c] + red[1][r][c] + red[2][r][c] + red[3][r][c];
        int row = row0 + r;
        hws[(size_t)row * NH + c] = __float2half(s * dsq[row]);
    }
}

// wave per dst node, 4 edges in flight: lanes split into 4 groups of 16;
// group g handles edge j+g, each lane loads 8B (4 fp16 feats). Cross-group
// reduce via shfl_xor(16,32); lanes 0-15 write float4.
__global__ __launch_bounds__(256) void gather_agg(const int* __restrict__ rowptr,
                                                  const int* __restrict__ csr_src,
                                                  const __half* __restrict__ hws,
                                                  const float* __restrict__ dsq,
                                                  const float* __restrict__ b,
                                                  float* __restrict__ outbuf, int n) {
    int node = blockIdx.x * 4 + (threadIdx.x >> 6);
    int lane = threadIdx.x & 63;
    if (node >= n) return;
    int g  = lane >> 4;          // edge slot 0..3
    int fl = (lane & 15) << 2;   // feature base
    int beg = rowptr[node], end = rowptr[node + 1];

    float ax = 0.f, ay = 0.f, az = 0.f, aw = 0.f;
    if (g == 0) {  // self-loop term
        uint2 rv = *(const uint2*)(hws + (size_t)node * NH + fl);
        float2 f0 = __half22float2(*(const __half2*)&rv.x);
        float2 f1 = __half22float2(*(const __half2*)&rv.y);
        ax = f0.x; ay = f0.y; az = f1.x; aw = f1.y;
    }
    int jend = beg + ((end - beg) & ~3);
#pragma unroll 2
    for (int j = beg; j < jend; j += 4) {
        int s = csr_src[j + g];
        uint2 rv = *(const uint2*)(hws + (size_t)s * NH + fl);
        float2 f0 = __half22float2(*(const __half2*)&rv.x);
        float2 f1 = __half22float2(*(const __half2*)&rv.y);
        ax += f0.x; ay += f0.y; az += f1.x; aw += f1.y;
    }
    if (jend + g < end) {  // tail (exec-masked)
        int s = csr_src[jend + g];
        uint2 rv = *(const uint2*)(hws + (size_t)s * NH + fl);
        float2 f0 = __half22float2(*(const __half2*)&rv.x);
        float2 f1 = __half22float2(*(const __half2*)&rv.y);
        ax += f0.x; ay += f0.y; az += f1.x; aw += f1.y;
    }
    // reduce the 4 edge-groups
    ax += __shfl_xor(ax, 16); ay += __shfl_xor(ay, 16);
    az += __shfl_xor(az, 16); aw += __shfl_xor(aw, 16);
    ax += __shfl_xor(ax, 32); ay += __shfl_xor(ay, 32);
    az += __shfl_xor(az, 32); aw += __shfl_xor(aw, 32);

    if (lane < 16) {
        float ds = dsq[node];
        float4 bb = *(const float4*)(b + fl);
        float4 o;
        o.x = fmaxf(ds * ax + bb.x, 0.f);
        o.y = fmaxf(ds * ay + bb.y, 0.f);
        o.z = fmaxf(ds * az + bb.z, 0.f);
        o.w = fmaxf(ds * aw + bb.w, 0.f);
        *(float4*)(outbuf + (size_t)node * NH + fl) = o;
    }
}

extern "C" void kernel_launch(void* const* d_in, const int* in_sizes, int n_in,
                              void* d_out, int out_size, void* d_ws, size_t ws_size,
                              hipStream_t stream) {
    const float* x     = (const float*)d_in[0];
    const int*   ei    = (const int*)d_in[1];
    const float* W_emb = (const float*)d_in[2];
    const float* b_emb = (const float*)d_in[3];
    const float* Ws    = (const float*)d_in[4];
    const float* bs    = (const float*)d_in[5];
    float* out = (float*)d_out;

    const int* src = ei;
    const int* dst = ei + NE;

    const int NSCAN = (NN + SB - 1) / SB;  // 196

    char* w = (char*)d_ws;
    int*    cnt      = (int*)w;               w += NN * 4;
    int*    rowptr   = (int*)w;               w += (NN + 1) * 4;
    int*    local    = (int*)w;               w += NN * 4;
    int*    blk_sums = (int*)w;               w += 256 * 4;
    int*    bcur     = (int*)w;               w += 256 * 4;
    float*  dsq      = (float*)w;             w += NN * 4;
    float*  Wc       = (float*)w;             w += NF * NH * 4;
    float*  bc       = (float*)w;             w += NH * 4;
    int*    csr_src  = (int*)w;               w += NE * 4;
    int*    tmp      = (int*)w;               w += (size_t)NE * 4;
    float*  A        = (float*)w;             w += (size_t)NN * NH * 4;
    __half* Bh       = (__half*)w;

    // --- CSR build (once per call) ---
    zero_cnt<<<(NN + 255) / 256, 256, 0, stream>>>(cnt, NN);
    count_deg<<<(NE + 255) / 256, 256, 0, stream>>>(dst, cnt, NE);
    compute_dsq<<<(NN + 255) / 256, 256, 0, stream>>>(cnt, dsq, NN);
    scan1<<<NSCAN, 256, 0, stream>>>(cnt, local, blk_sums, NN);
    scan2<<<1, 256, 0, stream>>>(blk_sums, NSCAN);
    scan3<<<(NN + 255) / 256, 256, 0, stream>>>(local, blk_sums, rowptr, bcur, NN);
    part_bucket<<<(NE + CHA - 1) / CHA, 256, 0, stream>>>(src, dst, bcur, tmp, NE);
    bucket_scatter<<<NBUCK, 256, 0, stream>>>(rowptr, tmp, csr_src);

    // --- fold embed into layer-0 weights ---
    combine_w<<<NF / 4, 256, 0, stream>>>(W_emb, b_emb, Ws, Wc, bc);

    // --- layer 0 (fused with embedding) ---
    fuse0_gemm<<<NN / 16, 256, 0, stream>>>(x, Wc, bc, dsq, Bh);
    gather_agg<<<(NN + 3) / 4, 256, 0, stream>>>(rowptr, csr_src, Bh,
                                                 dsq, bs, A, NN);

    // --- layers 1,2 ---
    for (int l = 1; l < 3; ++l) {
        layer_gemm<<<NN / 16, 256, 0, stream>>>(A, Ws + l * NH * NH, dsq, Bh);
        float* dbuf = (l == 2) ? out : A;
        gather_agg<<<(NN + 3) / 4, 256, 0, stream>>>(rowptr, csr_src, Bh,
                                                     dsq, bs + l * NH, dbuf, NN);
    }
}

// Round 8
// 304.170 us; speedup vs baseline: 4.7261x; 1.2423x over previous
//
#include <hip/hip_runtime.h>
#include <hip/hip_fp16.h>
#include <math.h>

#define NN 100000
#define NE 1600000
#define NF 128
#define NH 64
#define NBUCK 196     // ceil(NN / 512)
#define CHA 8192      // edges per block in partition pass
#define CAP 10240     // per-bucket capacity (mean 8163, +23 sigma)

__global__ __launch_bounds__(256) void zero_bcnt(int* bcnt) {
    int t = threadIdx.x;
    if (t < NBUCK) bcnt[t] = 0;
}

// Pass A: partition edges into 512-node dst-buckets (fixed-capacity regions).
// Packed entry: (dst & 511) << 17 | src   (src < 2^17).
__global__ __launch_bounds__(256) void part_bucket2(const int* __restrict__ src,
                                                    const int* __restrict__ dst,
                                                    int* __restrict__ bcnt,
                                                    int* __restrict__ tmp, int E) {
    __shared__ int hist[NBUCK];
    __shared__ int base[NBUCK];
    int t = threadIdx.x;
    int e0 = blockIdx.x * CHA;
    int e1 = min(e0 + CHA, E);
    if (t < NBUCK) hist[t] = 0;
    __syncthreads();
    for (int i = e0 + t; i < e1; i += 256) {
        atomicAdd(&hist[dst[i] >> 9], 1);
    }
    __syncthreads();
    if (t < NBUCK) {
        int h = hist[t];
        base[t] = h ? atomicAdd(&bcnt[t], h) : 0;
        hist[t] = 0;
    }
    __syncthreads();
    for (int i = e0 + t; i < e1; i += 256) {
        int d = dst[i];
        int b = d >> 9;
        int r = atomicAdd(&hist[b], 1);
        tmp[b * CAP + base[b] + r] = ((d & 511) << 17) | src[i];
    }
}

// exclusive scan of the 196 bucket counts -> CSR base per bucket
__global__ __launch_bounds__(256) void scan_buckets(const int* __restrict__ bcnt,
                                                    int* __restrict__ cbase,
                                                    int* __restrict__ rowptr) {
    __shared__ int s[256];
    int t = threadIdx.x;
    s[t] = (t < NBUCK) ? bcnt[t] : 0;
    __syncthreads();
    for (int off = 1; off < 256; off <<= 1) {
        int v = (t >= off) ? s[t - off] : 0;
        __syncthreads();
        s[t] += v;
        __syncthreads();
    }
    if (t < NBUCK) cbase[t] = (t == 0) ? 0 : s[t - 1];
    if (t == 0) rowptr[NN] = NE;
}

// Pass B: one block per bucket. Stage entries in LDS, per-node degree histogram
// (-> rowptr, dsq), LDS scan, LDS-cursor scatter into csr_src.
__global__ __launch_bounds__(256) void bucket_finalize(const int* __restrict__ bcnt,
                                                       const int* __restrict__ cbase,
                                                       const int* __restrict__ tmp,
                                                       int* __restrict__ rowptr,
                                                       float* __restrict__ dsq,
                                                       int* __restrict__ csr_src) {
    __shared__ int ebuf[CAP];   // 40 KB
    __shared__ int hcnt[512];
    __shared__ int hoff[512];
    __shared__ int s[256];
    int b = blockIdx.x, t = threadIdx.x;
    int cb = bcnt[b];
    int base = cbase[b];
    const int* tsrc = tmp + b * CAP;
    for (int i = t; i < cb; i += 256) ebuf[i] = tsrc[i];
    hcnt[t] = 0;
    hcnt[t + 256] = 0;
    __syncthreads();
    for (int i = t; i < cb; i += 256) atomicAdd(&hcnt[ebuf[i] >> 17], 1);
    __syncthreads();
    int c0 = hcnt[2 * t], c1 = hcnt[2 * t + 1];
    s[t] = c0 + c1;
    __syncthreads();
    for (int off = 1; off < 256; off <<= 1) {
        int v = (t >= off) ? s[t - off] : 0;
        __syncthreads();
        s[t] += v;
        __syncthreads();
    }
    int pb = (t == 0) ? 0 : s[t - 1];
    hoff[2 * t] = pb;
    hoff[2 * t + 1] = pb + c0;
    __syncthreads();
    int nodelo = b << 9;
    int nnodes = min(512, NN - nodelo);
    for (int i = t; i < nnodes; i += 256) {
        rowptr[nodelo + i] = base + hoff[i];
        dsq[nodelo + i] = rsqrtf((float)hcnt[i] + 1.0f);
    }
    __syncthreads();
    for (int i = t; i < cb; i += 256) {
        int e = ebuf[i];
        int dlow = e >> 17;
        int p = atomicAdd(&hoff[dlow], 1);
        csr_src[base + p] = e & 0x1FFFF;
    }
}

// Wc = We @ W0  [128x64], bc = be @ W0 [64]  (fold embed into layer-0 GEMM)
__global__ __launch_bounds__(256) void combine_w(const float* __restrict__ We,
                                                 const float* __restrict__ be,
                                                 const float* __restrict__ W0,
                                                 float* __restrict__ Wc,
                                                 float* __restrict__ bc) {
    __shared__ float w0[NH * NH];
    int t = threadIdx.x;
    for (int i = t; i < NH * NH; i += 256) w0[i] = W0[i];
    __syncthreads();
    int row = blockIdx.x * 4 + (t >> 6);  // We row, grid = 32
    int col = t & 63;
    float a = 0.f;
#pragma unroll 8
    for (int k = 0; k < NH; ++k) a += We[row * NH + k] * w0[k * NH + col];
    Wc[row * NH + col] = a;
    if (blockIdx.x == 0 && t < NH) {
        float s = 0.f;
        for (int k = 0; k < NH; ++k) s += be[k] * w0[k * NH + t];
        bc[t] = s;
    }
}

// hws0 = (x @ Wc + bc) * dsq[row], fp16 out.  K=128, LDS-staged x tile.
__global__ __launch_bounds__(256) void fuse0_gemm(const float* __restrict__ x,
                                                  const float* __restrict__ Wc,
                                                  const float* __restrict__ bc,
                                                  const float* __restrict__ dsq,
                                                  __half* __restrict__ hws) {
    __shared__ float tile[16 * NF];          // 8 KB
    __shared__ float red[4][16][NH];         // 16 KB
    int t = threadIdx.x;
    int lane = t & 63;
    int wave = __builtin_amdgcn_readfirstlane(t >> 6);
    int row0 = blockIdx.x * 16;

    const float4* xsrc = (const float4*)(x + (size_t)row0 * NF);
    float4* t4 = (float4*)tile;
    t4[t] = xsrc[t];
    t4[t + 256] = xsrc[t + 256];

    float Wreg[32];
#pragma unroll
    for (int kk = 0; kk < 32; ++kk) Wreg[kk] = Wc[(wave * 32 + kk) * NH + lane];
    __syncthreads();

    float acc[16];
#pragma unroll
    for (int r = 0; r < 16; ++r) {
        const float4* rp = (const float4*)(tile + r * NF + wave * 32);
        float a = 0.f;
#pragma unroll
        for (int q = 0; q < 8; ++q) {
            float4 v = rp[q];
            a += v.x * Wreg[q * 4 + 0];
            a += v.y * Wreg[q * 4 + 1];
            a += v.z * Wreg[q * 4 + 2];
            a += v.w * Wreg[q * 4 + 3];
        }
        acc[r] = a;
    }
#pragma unroll
    for (int r = 0; r < 16; ++r) red[wave][r][lane] = acc[r];
    __syncthreads();
#pragma unroll
    for (int i = 0; i < 4; ++i) {
        int o = i * 256 + t;
        int r = o >> 6, c = o & 63;
        float s = red[0][r][c] + red[1][r][c] + red[2][r][c] + red[3][r][c];
        int row = row0 + r;
        hws[(size_t)row * NH + c] = __float2half((s + bc[c]) * dsq[row]);
    }
}

// hws = (h @ W) * dsq[row], fp16 out.  K=64, LDS-staged h tile.
__global__ __launch_bounds__(256) void layer_gemm(const float* __restrict__ h,
                                                  const float* __restrict__ W,
                                                  const float* __restrict__ dsq,
                                                  __half* __restrict__ hws) {
    __shared__ float tile[16 * NH];          // 4 KB
    __shared__ float red[4][16][NH];         // 16 KB
    int t = threadIdx.x;
    int lane = t & 63;
    int wave = __builtin_amdgcn_readfirstlane(t >> 6);
    int row0 = blockIdx.x * 16;

    const float4* hsrc = (const float4*)(h + (size_t)row0 * NH);
    float4* t4 = (float4*)tile;
    t4[t] = hsrc[t];

    float Wreg[16];
#pragma unroll
    for (int kk = 0; kk < 16; ++kk) Wreg[kk] = W[(wave * 16 + kk) * NH + lane];
    __syncthreads();

    float acc[16];
#pragma unroll
    for (int r = 0; r < 16; ++r) {
        const float4* rp = (const float4*)(tile + r * NH + wave * 16);
        float a = 0.f;
#pragma unroll
        for (int q = 0; q < 4; ++q) {
            float4 v = rp[q];
            a += v.x * Wreg[q * 4 + 0];
            a += v.y * Wreg[q * 4 + 1];
            a += v.z * Wreg[q * 4 + 2];
            a += v.w * Wreg[q * 4 + 3];
        }
        acc[r] = a;
    }
#pragma unroll
    for (int r = 0; r < 16; ++r) red[wave][r][lane] = acc[r];
    __syncthreads();
#pragma unroll
    for (int i = 0; i < 4; ++i) {
        int o = i * 256 + t;
        int r = o >> 6, c = o & 63;
        float s = red[0][r][c] + red[1][r][c] + red[2][r][c] + red[3][r][c];
        int row = row0 + r;
        hws[(size_t)row * NH + c] = __float2half(s * dsq[row]);
    }
}

// wave per dst node, 4 edges in flight: lanes split into 4 groups of 16;
// group g handles edge j+g, each lane loads 8B (4 fp16 feats). Cross-group
// reduce via shfl_xor(16,32); lanes 0-15 write float4.
__global__ __launch_bounds__(256) void gather_agg(const int* __restrict__ rowptr,
                                                  const int* __restrict__ csr_src,
                                                  const __half* __restrict__ hws,
                                                  const float* __restrict__ dsq,
                                                  const float* __restrict__ b,
                                                  float* __restrict__ outbuf, int n) {
    int node = blockIdx.x * 4 + (threadIdx.x >> 6);
    int lane = threadIdx.x & 63;
    if (node >= n) return;
    int g  = lane >> 4;          // edge slot 0..3
    int fl = (lane & 15) << 2;   // feature base
    int beg = rowptr[node], end = rowptr[node + 1];

    float ax = 0.f, ay = 0.f, az = 0.f, aw = 0.f;
    if (g == 0) {  // self-loop term
        uint2 rv = *(const uint2*)(hws + (size_t)node * NH + fl);
        float2 f0 = __half22float2(*(const __half2*)&rv.x);
        float2 f1 = __half22float2(*(const __half2*)&rv.y);
        ax = f0.x; ay = f0.y; az = f1.x; aw = f1.y;
    }
    int jend = beg + ((end - beg) & ~3);
#pragma unroll 2
    for (int j = beg; j < jend; j += 4) {
        int s = csr_src[j + g];
        uint2 rv = *(const uint2*)(hws + (size_t)s * NH + fl);
        float2 f0 = __half22float2(*(const __half2*)&rv.x);
        float2 f1 = __half22float2(*(const __half2*)&rv.y);
        ax += f0.x; ay += f0.y; az += f1.x; aw += f1.y;
    }
    if (jend + g < end) {  // tail (exec-masked)
        int s = csr_src[jend + g];
        uint2 rv = *(const uint2*)(hws + (size_t)s * NH + fl);
        float2 f0 = __half22float2(*(const __half2*)&rv.x);
        float2 f1 = __half22float2(*(const __half2*)&rv.y);
        ax += f0.x; ay += f0.y; az += f1.x; aw += f1.y;
    }
    ax += __shfl_xor(ax, 16); ay += __shfl_xor(ay, 16);
    az += __shfl_xor(az, 16); aw += __shfl_xor(aw, 16);
    ax += __shfl_xor(ax, 32); ay += __shfl_xor(ay, 32);
    az += __shfl_xor(az, 32); aw += __shfl_xor(aw, 32);

    if (lane < 16) {
        float ds = dsq[node];
        float4 bb = *(const float4*)(b + fl);
        float4 o;
        o.x = fmaxf(ds * ax + bb.x, 0.f);
        o.y = fmaxf(ds * ay + bb.y, 0.f);
        o.z = fmaxf(ds * az + bb.z, 0.f);
        o.w = fmaxf(ds * aw + bb.w, 0.f);
        *(float4*)(outbuf + (size_t)node * NH + fl) = o;
    }
}

extern "C" void kernel_launch(void* const* d_in, const int* in_sizes, int n_in,
                              void* d_out, int out_size, void* d_ws, size_t ws_size,
                              hipStream_t stream) {
    const float* x     = (const float*)d_in[0];
    const int*   ei    = (const int*)d_in[1];
    const float* W_emb = (const float*)d_in[2];
    const float* b_emb = (const float*)d_in[3];
    const float* Ws    = (const float*)d_in[4];
    const float* bs    = (const float*)d_in[5];
    float* out = (float*)d_out;

    const int* src = ei;
    const int* dst = ei + NE;

    char* w = (char*)d_ws;
    int*    bcnt     = (int*)w;               w += 256 * 4;
    int*    cbase    = (int*)w;               w += 256 * 4;
    int*    rowptr   = (int*)w;               w += (NN + 1) * 4;
    float*  dsq      = (float*)w;             w += NN * 4;
    float*  Wc       = (float*)w;             w += NF * NH * 4;
    float*  bc       = (float*)w;             w += NH * 4;
    int*    csr_src  = (int*)w;               w += NE * 4;
    int*    tmp      = (int*)w;               w += (size_t)NBUCK * CAP * 4;
    float*  A        = (float*)w;             w += (size_t)NN * NH * 4;
    __half* Bh       = (__half*)w;

    // --- CSR build (once per call) ---
    zero_bcnt<<<1, 256, 0, stream>>>(bcnt);
    part_bucket2<<<(NE + CHA - 1) / CHA, 256, 0, stream>>>(src, dst, bcnt, tmp, NE);
    scan_buckets<<<1, 256, 0, stream>>>(bcnt, cbase, rowptr);
    bucket_finalize<<<NBUCK, 256, 0, stream>>>(bcnt, cbase, tmp, rowptr, dsq, csr_src);

    // --- fold embed into layer-0 weights ---
    combine_w<<<NF / 4, 256, 0, stream>>>(W_emb, b_emb, Ws, Wc, bc);

    // --- layer 0 (fused with embedding) ---
    fuse0_gemm<<<NN / 16, 256, 0, stream>>>(x, Wc, bc, dsq, Bh);
    gather_agg<<<(NN + 3) / 4, 256, 0, stream>>>(rowptr, csr_src, Bh,
                                                 dsq, bs, A, NN);

    // --- layers 1,2 ---
    for (int l = 1; l < 3; ++l) {
        layer_gemm<<<NN / 16, 256, 0, stream>>>(A, Ws + l * NH * NH, dsq, Bh);
        float* dbuf = (l == 2) ? out : A;
        gather_agg<<<(NN + 3) / 4, 256, 0, stream>>>(rowptr, csr_src, Bh,
                                                     dsq, bs + l * NH, dbuf, NN);
    }
}

// Round 9
// 295.841 us; speedup vs baseline: 4.8592x; 1.0282x over previous
//
#include <hip/hip_runtime.h>
#include <hip/hip_fp16.h>
#include <math.h>

#define NN 100000
#define NE 1600000
#define NF 128
#define NH 64
#define NBUCK 196     // ceil(NN / 512)
#define CHA 8192      // edges per block in partition pass
#define CAP 10240     // per-bucket capacity (mean 8163, +23 sigma)

__global__ __launch_bounds__(256) void zero_bcnt(int* bcnt) {
    int t = threadIdx.x;
    if (t < NBUCK) bcnt[t] = 0;
}

// Pass A: partition edges into 512-node dst-buckets (fixed-capacity regions).
// Packed entry: (dst & 511) << 17 | src   (src < 2^17).
__global__ __launch_bounds__(256) void part_bucket2(const int* __restrict__ src,
                                                    const int* __restrict__ dst,
                                                    int* __restrict__ bcnt,
                                                    int* __restrict__ tmp, int E) {
    __shared__ int hist[NBUCK];
    __shared__ int base[NBUCK];
    int t = threadIdx.x;
    int e0 = blockIdx.x * CHA;
    int e1 = min(e0 + CHA, E);
    if (t < NBUCK) hist[t] = 0;
    __syncthreads();
    for (int i = e0 + t; i < e1; i += 256) {
        atomicAdd(&hist[dst[i] >> 9], 1);
    }
    __syncthreads();
    if (t < NBUCK) {
        int h = hist[t];
        base[t] = h ? atomicAdd(&bcnt[t], h) : 0;
        hist[t] = 0;
    }
    __syncthreads();
    for (int i = e0 + t; i < e1; i += 256) {
        int d = dst[i];
        int b = d >> 9;
        int r = atomicAdd(&hist[b], 1);
        tmp[b * CAP + base[b] + r] = ((d & 511) << 17) | src[i];
    }
}

// exclusive scan of the 196 bucket counts -> CSR base per bucket
__global__ __launch_bounds__(256) void scan_buckets(const int* __restrict__ bcnt,
                                                    int* __restrict__ cbase,
                                                    int* __restrict__ rowptr) {
    __shared__ int s[256];
    int t = threadIdx.x;
    s[t] = (t < NBUCK) ? bcnt[t] : 0;
    __syncthreads();
    for (int off = 1; off < 256; off <<= 1) {
        int v = (t >= off) ? s[t - off] : 0;
        __syncthreads();
        s[t] += v;
        __syncthreads();
    }
    if (t < NBUCK) cbase[t] = (t == 0) ? 0 : s[t - 1];
    if (t == 0) rowptr[NN] = NE;
}

// Pass B: one block per bucket. Stage entries in LDS, per-node degree histogram
// (-> rowptr, dsq), LDS scan, LDS-cursor scatter into csr_src.
__global__ __launch_bounds__(256) void bucket_finalize(const int* __restrict__ bcnt,
                                                       const int* __restrict__ cbase,
                                                       const int* __restrict__ tmp,
                                                       int* __restrict__ rowptr,
                                                       float* __restrict__ dsq,
                                                       int* __restrict__ csr_src) {
    __shared__ int ebuf[CAP];   // 40 KB
    __shared__ int hcnt[512];
    __shared__ int hoff[512];
    __shared__ int s[256];
    int b = blockIdx.x, t = threadIdx.x;
    int cb = bcnt[b];
    int base = cbase[b];
    const int* tsrc = tmp + b * CAP;
    for (int i = t; i < cb; i += 256) ebuf[i] = tsrc[i];
    hcnt[t] = 0;
    hcnt[t + 256] = 0;
    __syncthreads();
    for (int i = t; i < cb; i += 256) atomicAdd(&hcnt[ebuf[i] >> 17], 1);
    __syncthreads();
    int c0 = hcnt[2 * t], c1 = hcnt[2 * t + 1];
    s[t] = c0 + c1;
    __syncthreads();
    for (int off = 1; off < 256; off <<= 1) {
        int v = (t >= off) ? s[t - off] : 0;
        __syncthreads();
        s[t] += v;
        __syncthreads();
    }
    int pb = (t == 0) ? 0 : s[t - 1];
    hoff[2 * t] = pb;
    hoff[2 * t + 1] = pb + c0;
    __syncthreads();
    int nodelo = b << 9;
    int nnodes = min(512, NN - nodelo);
    for (int i = t; i < nnodes; i += 256) {
        rowptr[nodelo + i] = base + hoff[i];
        dsq[nodelo + i] = rsqrtf((float)hcnt[i] + 1.0f);
    }
    __syncthreads();
    for (int i = t; i < cb; i += 256) {
        int e = ebuf[i];
        int dlow = e >> 17;
        int p = atomicAdd(&hoff[dlow], 1);
        csr_src[base + p] = e & 0x1FFFF;
    }
}

// Wc = We @ W0  [128x64], bc = be @ W0 [64]  (fold embed into layer-0 GEMM)
__global__ __launch_bounds__(256) void combine_w(const float* __restrict__ We,
                                                 const float* __restrict__ be,
                                                 const float* __restrict__ W0,
                                                 float* __restrict__ Wc,
                                                 float* __restrict__ bc) {
    __shared__ float w0[NH * NH];
    int t = threadIdx.x;
    for (int i = t; i < NH * NH; i += 256) w0[i] = W0[i];
    __syncthreads();
    int row = blockIdx.x * 4 + (t >> 6);  // We row, grid = 32
    int col = t & 63;
    float a = 0.f;
#pragma unroll 8
    for (int k = 0; k < NH; ++k) a += We[row * NH + k] * w0[k * NH + col];
    Wc[row * NH + col] = a;
    if (blockIdx.x == 0 && t < NH) {
        float s = 0.f;
        for (int k = 0; k < NH; ++k) s += be[k] * w0[k * NH + t];
        bc[t] = s;
    }
}

// hws0 = (x @ Wc + bc) * dsq[row], fp16 out.  K=128, LDS-staged x tile.
__global__ __launch_bounds__(256) void fuse0_gemm(const float* __restrict__ x,
                                                  const float* __restrict__ Wc,
                                                  const float* __restrict__ bc,
                                                  const float* __restrict__ dsq,
                                                  __half* __restrict__ hws) {
    __shared__ float tile[16 * NF];          // 8 KB
    __shared__ float red[4][16][NH];         // 16 KB
    int t = threadIdx.x;
    int lane = t & 63;
    int wave = __builtin_amdgcn_readfirstlane(t >> 6);
    int row0 = blockIdx.x * 16;

    const float4* xsrc = (const float4*)(x + (size_t)row0 * NF);
    float4* t4 = (float4*)tile;
    t4[t] = xsrc[t];
    t4[t + 256] = xsrc[t + 256];

    float Wreg[32];
#pragma unroll
    for (int kk = 0; kk < 32; ++kk) Wreg[kk] = Wc[(wave * 32 + kk) * NH + lane];
    __syncthreads();

    float acc[16];
#pragma unroll
    for (int r = 0; r < 16; ++r) {
        const float4* rp = (const float4*)(tile + r * NF + wave * 32);
        float a = 0.f;
#pragma unroll
        for (int q = 0; q < 8; ++q) {
            float4 v = rp[q];
            a += v.x * Wreg[q * 4 + 0];
            a += v.y * Wreg[q * 4 + 1];
            a += v.z * Wreg[q * 4 + 2];
            a += v.w * Wreg[q * 4 + 3];
        }
        acc[r] = a;
    }
#pragma unroll
    for (int r = 0; r < 16; ++r) red[wave][r][lane] = acc[r];
    __syncthreads();
#pragma unroll
    for (int i = 0; i < 4; ++i) {
        int o = i * 256 + t;
        int r = o >> 6, c = o & 63;
        float s = red[0][r][c] + red[1][r][c] + red[2][r][c] + red[3][r][c];
        int row = row0 + r;
        hws[(size_t)row * NH + c] = __float2half((s + bc[c]) * dsq[row]);
    }
}

// hws = (h @ W) * dsq[row], fp16 out.  K=64, LDS-staged h tile.
__global__ __launch_bounds__(256) void layer_gemm(const float* __restrict__ h,
                                                  const float* __restrict__ W,
                                                  const float* __restrict__ dsq,
                                                  __half* __restrict__ hws) {
    __shared__ float tile[16 * NH];          // 4 KB
    __shared__ float red[4][16][NH];         // 16 KB
    int t = threadIdx.x;
    int lane = t & 63;
    int wave = __builtin_amdgcn_readfirstlane(t >> 6);
    int row0 = blockIdx.x * 16;

    const float4* hsrc = (const float4*)(h + (size_t)row0 * NH);
    float4* t4 = (float4*)tile;
    t4[t] = hsrc[t];

    float Wreg[16];
#pragma unroll
    for (int kk = 0; kk < 16; ++kk) Wreg[kk] = W[(wave * 16 + kk) * NH + lane];
    __syncthreads();

    float acc[16];
#pragma unroll
    for (int r = 0; r < 16; ++r) {
        const float4* rp = (const float4*)(tile + r * NH + wave * 16);
        float a = 0.f;
#pragma unroll
        for (int q = 0; q < 4; ++q) {
            float4 v = rp[q];
            a += v.x * Wreg[q * 4 + 0];
            a += v.y * Wreg[q * 4 + 1];
            a += v.z * Wreg[q * 4 + 2];
            a += v.w * Wreg[q * 4 + 3];
        }
        acc[r] = a;
    }
#pragma unroll
    for (int r = 0; r < 16; ++r) red[wave][r][lane] = acc[r];
    __syncthreads();
#pragma unroll
    for (int i = 0; i < 4; ++i) {
        int o = i * 256 + t;
        int r = o >> 6, c = o & 63;
        float s = red[0][r][c] + red[1][r][c] + red[2][r][c] + red[3][r][c];
        int row = row0 + r;
        hws[(size_t)row * NH + c] = __float2half(s * dsq[row]);
    }
}

// wave per dst node, 8 edges in flight: lanes split into 8 groups of 8;
// group g handles edge j+g, each lane loads 16B (8 fp16 feats). Cross-group
// reduce via shfl_xor(8,16,32); lanes 0-7 write 2x float4.
__global__ __launch_bounds__(256) void gather_agg(const int* __restrict__ rowptr,
                                                  const int* __restrict__ csr_src,
                                                  const __half* __restrict__ hws,
                                                  const float* __restrict__ dsq,
                                                  const float* __restrict__ b,
                                                  float* __restrict__ outbuf, int n) {
    int node = blockIdx.x * 4 + (threadIdx.x >> 6);
    int lane = threadIdx.x & 63;
    if (node >= n) return;
    int g  = lane >> 3;          // edge slot 0..7
    int fl = (lane & 7) << 3;    // feature base (8 fp16 = 16B)
    int beg = rowptr[node], end = rowptr[node + 1];

    float a0 = 0.f, a1 = 0.f, a2 = 0.f, a3 = 0.f;
    float a4 = 0.f, a5 = 0.f, a6 = 0.f, a7 = 0.f;

#define ADDROW(sidx)                                                         \
    {                                                                        \
        uint4 rv = *(const uint4*)(hws + (size_t)(sidx) * NH + fl);          \
        float2 f0 = __half22float2(*(const __half2*)&rv.x);                  \
        float2 f1 = __half22float2(*(const __half2*)&rv.y);                  \
        float2 f2 = __half22float2(*(const __half2*)&rv.z);                  \
        float2 f3 = __half22float2(*(const __half2*)&rv.w);                  \
        a0 += f0.x; a1 += f0.y; a2 += f1.x; a3 += f1.y;                      \
        a4 += f2.x; a5 += f2.y; a6 += f3.x; a7 += f3.y;                      \
    }

    if (g == 0) ADDROW(node);  // self-loop term
    int jend = beg + ((end - beg) & ~7);
#pragma unroll 2
    for (int j = beg; j < jend; j += 8) {
        int s = csr_src[j + g];
        ADDROW(s);
    }
    if (jend + g < end) {  // tail (exec-masked)
        int s = csr_src[jend + g];
        ADDROW(s);
    }
#undef ADDROW

    // reduce the 8 edge-groups
    a0 += __shfl_xor(a0, 8);  a1 += __shfl_xor(a1, 8);
    a2 += __shfl_xor(a2, 8);  a3 += __shfl_xor(a3, 8);
    a4 += __shfl_xor(a4, 8);  a5 += __shfl_xor(a5, 8);
    a6 += __shfl_xor(a6, 8);  a7 += __shfl_xor(a7, 8);
    a0 += __shfl_xor(a0, 16); a1 += __shfl_xor(a1, 16);
    a2 += __shfl_xor(a2, 16); a3 += __shfl_xor(a3, 16);
    a4 += __shfl_xor(a4, 16); a5 += __shfl_xor(a5, 16);
    a6 += __shfl_xor(a6, 16); a7 += __shfl_xor(a7, 16);
    a0 += __shfl_xor(a0, 32); a1 += __shfl_xor(a1, 32);
    a2 += __shfl_xor(a2, 32); a3 += __shfl_xor(a3, 32);
    a4 += __shfl_xor(a4, 32); a5 += __shfl_xor(a5, 32);
    a6 += __shfl_xor(a6, 32); a7 += __shfl_xor(a7, 32);

    if (lane < 8) {
        float ds = dsq[node];
        float4 b0 = *(const float4*)(b + fl);
        float4 b1 = *(const float4*)(b + fl + 4);
        float4 o0, o1;
        o0.x = fmaxf(ds * a0 + b0.x, 0.f);
        o0.y = fmaxf(ds * a1 + b0.y, 0.f);
        o0.z = fmaxf(ds * a2 + b0.z, 0.f);
        o0.w = fmaxf(ds * a3 + b0.w, 0.f);
        o1.x = fmaxf(ds * a4 + b1.x, 0.f);
        o1.y = fmaxf(ds * a5 + b1.y, 0.f);
        o1.z = fmaxf(ds * a6 + b1.z, 0.f);
        o1.w = fmaxf(ds * a7 + b1.w, 0.f);
        *(float4*)(outbuf + (size_t)node * NH + fl) = o0;
        *(float4*)(outbuf + (size_t)node * NH + fl + 4) = o1;
    }
}

extern "C" void kernel_launch(void* const* d_in, const int* in_sizes, int n_in,
                              void* d_out, int out_size, void* d_ws, size_t ws_size,
                              hipStream_t stream) {
    const float* x     = (const float*)d_in[0];
    const int*   ei    = (const int*)d_in[1];
    const float* W_emb = (const float*)d_in[2];
    const float* b_emb = (const float*)d_in[3];
    const float* Ws    = (const float*)d_in[4];
    const float* bs    = (const float*)d_in[5];
    float* out = (float*)d_out;

    const int* src = ei;
    const int* dst = ei + NE;

    char* w = (char*)d_ws;
    int*    bcnt     = (int*)w;               w += 256 * 4;
    int*    cbase    = (int*)w;               w += 256 * 4;
    int*    rowptr   = (int*)w;               w += (NN + 1) * 4;
    float*  dsq      = (float*)w;             w += NN * 4;
    float*  Wc       = (float*)w;             w += NF * NH * 4;
    float*  bc       = (float*)w;             w += NH * 4;
    int*    csr_src  = (int*)w;               w += NE * 4;
    int*    tmp      = (int*)w;               w += (size_t)NBUCK * CAP * 4;
    float*  A        = (float*)w;             w += (size_t)NN * NH * 4;
    __half* Bh       = (__half*)w;

    // --- CSR build (once per call) ---
    zero_bcnt<<<1, 256, 0, stream>>>(bcnt);
    part_bucket2<<<(NE + CHA - 1) / CHA, 256, 0, stream>>>(src, dst, bcnt, tmp, NE);
    scan_buckets<<<1, 256, 0, stream>>>(bcnt, cbase, rowptr);
    bucket_finalize<<<NBUCK, 256, 0, stream>>>(bcnt, cbase, tmp, rowptr, dsq, csr_src);

    // --- fold embed into layer-0 weights ---
    combine_w<<<NF / 4, 256, 0, stream>>>(W_emb, b_emb, Ws, Wc, bc);

    // --- layer 0 (fused with embedding) ---
    fuse0_gemm<<<NN / 16, 256, 0, stream>>>(x, Wc, bc, dsq, Bh);
    gather_agg<<<(NN + 3) / 4, 256, 0, stream>>>(rowptr, csr_src, Bh,
                                                 dsq, bs, A, NN);

    // --- layers 1,2 ---
    for (int l = 1; l < 3; ++l) {
        layer_gemm<<<NN / 16, 256, 0, stream>>>(A, Ws + l * NH * NH, dsq, Bh);
        float* dbuf = (l == 2) ? out : A;
        gather_agg<<<(NN + 3) / 4, 256, 0, stream>>>(rowptr, csr_src, Bh,
                                                     dsq, bs + l * NH, dbuf, NN);
    }
}